// Round 5
// baseline (1499.312 us; speedup 1.0000x reference)
//
#include <hip/hip_runtime.h>
#include <hip/hip_fp8.h>

#define DIM 128
#define LN_EPS 1e-5f

typedef __attribute__((ext_vector_type(8))) short s16x8;   // 8 bf16 in 4 VGPRs
typedef __attribute__((ext_vector_type(4))) float f32x4;
typedef __attribute__((ext_vector_type(2))) float f32x2;
typedef __attribute__((ext_vector_type(4))) unsigned int u32x4;
typedef __attribute__((ext_vector_type(2))) unsigned int u32x2;

__device__ __forceinline__ unsigned short f2bf(float f) {
    unsigned u = __float_as_uint(f);
    unsigned r = u + 0x7fffu + ((u >> 16) & 1u);   // round-to-nearest-even
    return (unsigned short)(r >> 16);
}
__device__ __forceinline__ float bf2f(unsigned short b) {
    return __uint_as_float(((unsigned)b) << 16);
}
__device__ __forceinline__ unsigned char f2fp8(float f) {
    return (unsigned char)__hip_cvt_float_to_fp8(f, __HIP_SATFINITE, __HIP_E4M3);
}
// accumulate 4 fp8 bytes (linear col order) into a[0..3]
__device__ __forceinline__ void acc_fp8x4(float* a, unsigned v) {
    f32x2 lo = __builtin_amdgcn_cvt_pk_f32_fp8(v, false);  // bytes 0,1
    f32x2 hi = __builtin_amdgcn_cvt_pk_f32_fp8(v, true);   // bytes 2,3
    a[0] += lo[0]; a[1] += lo[1]; a[2] += hi[0]; a[3] += hi[1];
}
// accumulate a full u32x4 (16 fp8 bytes) into a[0..15]
__device__ __forceinline__ void acc_fp8x16(float* a, u32x4 v) {
    acc_fp8x4(a + 0,  v[0]);
    acc_fp8x4(a + 4,  v[1]);
    acc_fp8x4(a + 8,  v[2]);
    acc_fp8x4(a + 12, v[3]);
}

// ---------------- monolithic persistent kernel ----------------
// One dispatch for the whole pipeline. Grid is sized to be fully co-resident
// (__launch_bounds__(256,4) caps VGPR at 128 -> 4 blocks/CU; grid <= occupancy
// cap from the runtime API). Inter-phase ordering via a device-scope arrival
// barrier (epoch counter, zeroed by host memset before launch).

struct GParams {
    const float* x;
    const int* e_src; const int* e_dst;
    const float* in_w; const float* in_b;
    const float* w1; const float* b1;
    const float* w2; const float* b2;
    const float* ln_g; const float* ln_b;
    float* out;
    unsigned short* hb0; unsigned short* hb1;
    unsigned char* h8a; unsigned char* h8b;
    int* gbar;
    int* counts; int* rowptr; int* cursor; float* dinv;
    int* srcidx; int* bsum; int* bofs;
    unsigned short* wt; unsigned short* mbuf;
    int N, E, L;
};

__device__ __forceinline__ void gsync(int* bar, int nb, int& epoch) {
    __syncthreads();
    if (threadIdx.x == 0) {
        ++epoch;
        __hip_atomic_fetch_add(bar, 1, __ATOMIC_RELEASE, __HIP_MEMORY_SCOPE_AGENT);
        while (__hip_atomic_load(bar, __ATOMIC_ACQUIRE, __HIP_MEMORY_SCOPE_AGENT) < epoch * nb)
            __builtin_amdgcn_s_sleep(1);
    }
    __syncthreads();
    __threadfence();   // acquire side for all threads (invalidate stale L1)
}

__global__ __launch_bounds__(256, 4) void gearnet_all(GParams p) {
    const int tid = threadIdx.x;
    const int bid = blockIdx.x;
    const int nb  = gridDim.x;
    const int gix = bid * 256 + tid;
    const int gstride = nb * 256;
    int epoch = 0;

    // shared: M[32][136] (8704 B) | P[32][136] (8704 B) | s1p (512 B) | s2p (512 B)
    __shared__ __align__(16) char shraw[18432];
    unsigned short (*M)[136] = (unsigned short (*)[136])shraw;
    unsigned short (*P)[136] = (unsigned short (*)[136])(shraw + 8704);
    float (*s1p)[32] = (float (*)[32])(shraw + 17408);
    float (*s2p)[32] = (float (*)[32])(shraw + 17920);
    int* wsum = (int*)shraw;   // scan phases reuse (disjoint in time)

    const int N = p.N, E = p.E, L = p.L;
    const int nMat = 2 * L + 1;
    const int lane = tid & 63;
    const int wv = tid >> 6;
    const int quad = lane >> 4, l16 = lane & 15;
    const int cs = wv * 32;

    // ===== R0: weight cvt (f32 row-major -> bf16 transposed) + count_deg =====
    for (int i = gix; i < nMat * 16384; i += gstride) {
        int mat = i >> 14, idx = i & 16383;
        const float* src = (mat == 0) ? p.in_w
                         : (mat <= L) ? p.w1 + ((size_t)(mat - 1) << 14)
                                      : p.w2 + ((size_t)(mat - 1 - L) << 14);
        int k = idx >> 7, n = idx & 127;
        p.wt[((size_t)mat << 14) + n * DIM + k] = f2bf(src[idx]);
    }
    for (int i = gix * 4; i < E; i += gstride * 4) {
        if (i + 3 < E) {
            int4 d = *(const int4*)(p.e_dst + i);
            atomicAdd(&p.counts[d.x], 1);
            atomicAdd(&p.counts[d.y], 1);
            atomicAdd(&p.counts[d.z], 1);
            atomicAdd(&p.counts[d.w], 1);
        } else {
            for (int j = i; j < E; ++j) atomicAdd(&p.counts[p.e_dst[j]], 1);
        }
    }
    gsync(p.gbar, nb, epoch);   // s0

    // ===== R1: scan partials (49 blocks) + input-proj GEMM (all blocks) =====
    const int nScan = (N + 1023) >> 10;
    for (int b = bid; b < nScan; b += nb) {
        int base = b * 1024 + tid * 4;
        int s_ = 0;
#pragma unroll
        for (int j = 0; j < 4; ++j) {
            int i = base + j;
            if (i < N) s_ += p.counts[i];
        }
#pragma unroll
        for (int off = 32; off > 0; off >>= 1) s_ += __shfl_xor(s_, off, 64);
        if (lane == 0) wsum[wv] = s_;
        __syncthreads();
        if (tid == 0) p.bsum[b] = wsum[0] + wsum[1] + wsum[2] + wsum[3];
        __syncthreads();
    }
    {
        int tiles = (N + 15) >> 4;
        for (int t = bid; t < tiles; t += nb) {
            int r0 = t << 4;
            int arow = r0 + l16;
            bool av = arow < N;
            f32x4 acc0 = (f32x4){0.f, 0.f, 0.f, 0.f};
            f32x4 acc1 = (f32x4){0.f, 0.f, 0.f, 0.f};
            const float4* xp = (const float4*)(p.x + ((size_t)(av ? arow : 0) << 7)) + quad * 2;
#pragma unroll
            for (int k0 = 0; k0 < 128; k0 += 32) {
                s16x8 a = {0, 0, 0, 0, 0, 0, 0, 0};
                if (av) {
                    float4 f0 = xp[k0 / 4];
                    float4 f1 = xp[k0 / 4 + 1];
                    a[0] = (short)f2bf(f0.x); a[1] = (short)f2bf(f0.y);
                    a[2] = (short)f2bf(f0.z); a[3] = (short)f2bf(f0.w);
                    a[4] = (short)f2bf(f1.x); a[5] = (short)f2bf(f1.y);
                    a[6] = (short)f2bf(f1.z); a[7] = (short)f2bf(f1.w);
                }
                s16x8 b0 = *(const s16x8*)(p.wt + ((size_t)(cs + l16) << 7) + quad * 8 + k0);
                s16x8 b1 = *(const s16x8*)(p.wt + ((size_t)(cs + 16 + l16) << 7) + quad * 8 + k0);
                acc0 = __builtin_amdgcn_mfma_f32_16x16x32_bf16(a, b0, acc0, 0, 0, 0);
                acc1 = __builtin_amdgcn_mfma_f32_16x16x32_bf16(a, b1, acc1, 0, 0, 0);
            }
#pragma unroll
            for (int c = 0; c < 2; ++c) {
                int col = cs + c * 16 + l16;
                float bv = p.in_b[col];
#pragma unroll
                for (int reg = 0; reg < 4; ++reg) {
                    int grow = r0 + quad * 4 + reg;
                    if (grow < N) {
                        float o = (c == 0 ? acc0[reg] : acc1[reg]) + bv;
                        p.hb0[((size_t)grow << 7) + col] = f2bf(o);
                        p.h8a[((size_t)grow << 7) + col] = f2fp8(o);
                    }
                }
            }
        }
    }
    gsync(p.gbar, nb, epoch);   // s1

    // ===== R2: scan block sums (block 0, wave 0) =====
    if (bid == 0 && tid < 64) {
        int carry = 0;
        for (int base = 0; base < nScan; base += 64) {
            int v = (base + lane < nScan) ? p.bsum[base + lane] : 0;
            int incl = v;
#pragma unroll
            for (int off = 1; off < 64; off <<= 1) {
                int t2 = __shfl_up(incl, off, 64);
                if (lane >= off) incl += t2;
            }
            if (base + lane < nScan) p.bofs[base + lane] = carry + incl - v;
            carry += __shfl(incl, 63, 64);
        }
        if (lane == 0) p.rowptr[N] = E;
    }
    gsync(p.gbar, nb, epoch);   // s2

    // ===== R3: scan final -> rowptr/cursor/dinv =====
    for (int b = bid; b < nScan; b += nb) {
        int base = b * 1024 + tid * 4;
        int v[4];
#pragma unroll
        for (int j = 0; j < 4; ++j) {
            int i = base + j;
            v[j] = (i < N) ? p.counts[i] : 0;
        }
        int tsum = v[0] + v[1] + v[2] + v[3];
        int incl = tsum;
#pragma unroll
        for (int off = 1; off < 64; off <<= 1) {
            int t2 = __shfl_up(incl, off, 64);
            if (lane >= off) incl += t2;
        }
        if (lane == 63) wsum[wv] = incl;
        __syncthreads();
        int wofs = 0;
        for (int w2i = 0; w2i < 4; ++w2i)
            if (w2i < wv) wofs += wsum[w2i];
        int excl = p.bofs[b] + wofs + (incl - tsum);
#pragma unroll
        for (int j = 0; j < 4; ++j) {
            int i = base + j;
            if (i < N) {
                p.rowptr[i] = excl;
                p.cursor[i] = excl;
                p.dinv[i] = 1.0f / (float)((v[j] > 1) ? v[j] : 1);
                excl += v[j];
            }
        }
        __syncthreads();
    }
    gsync(p.gbar, nb, epoch);   // s3

    // ===== R4: fill CSR =====
    for (int i = gix * 4; i < E; i += gstride * 4) {
        if (i + 3 < E) {
            int4 s4v = *(const int4*)(p.e_src + i);
            int4 d4v = *(const int4*)(p.e_dst + i);
            int p0 = atomicAdd(&p.cursor[d4v.x], 1); p.srcidx[p0] = s4v.x;
            int p1 = atomicAdd(&p.cursor[d4v.y], 1); p.srcidx[p1] = s4v.y;
            int p2 = atomicAdd(&p.cursor[d4v.z], 1); p.srcidx[p2] = s4v.z;
            int p3 = atomicAdd(&p.cursor[d4v.w], 1); p.srcidx[p3] = s4v.w;
        } else {
            for (int j = i; j < E; ++j) {
                int pp = atomicAdd(&p.cursor[p.e_dst[j]], 1);
                p.srcidx[pp] = p.e_src[j];
            }
        }
    }
    gsync(p.gbar, nb, epoch);   // s4

    // ===== layers =====
    unsigned short* hin = p.hb0;  unsigned char* h8in = p.h8a;
    unsigned short* hout = p.hb1; unsigned char* h8out = p.h8b;
    const int tiles32 = (N + 31) >> 5;
    const int gg = lane >> 3, li = lane & 7;   // gather: 8 groups/wave, 8 lanes/group

    for (int l = 0; l < L; ++l) {
        const unsigned short* W1t = p.wt + ((size_t)(1 + l) << 14);
        const unsigned short* W2t = p.wt + ((size_t)(1 + L + l) << 14);
        const float* B1 = p.b1 + l * DIM;
        const float* B2 = p.b2 + l * DIM;
        const float* G  = p.ln_g + l * DIM;
        const float* Bb = p.ln_b + l * DIM;
        float* out_f32 = (l == L - 1) ? p.out : nullptr;

        // ---- aggregate: full-row fp8 gather, 8 lanes/node, 2-deep pipeline ----
        for (int t = bid; t < tiles32; t += nb) {
            int nd = t * 32 + wv * 8 + gg;
            bool nv = nd < N;
            int e  = nv ? p.rowptr[nd] : 0;
            int ee = nv ? p.rowptr[nd + 1] : 0;
            float di = nv ? p.dinv[nd] : 0.f;
            const unsigned char* hsl = h8in + li * 16;

            float a[16];
#pragma unroll
            for (int j = 0; j < 16; ++j) a[j] = 0.f;

#define GIDX(jj) (((jj) < ee) ? p.srcidx[(jj)] : -1)
            int jA = e;
            int iA0 = GIDX(jA + 0), iA1 = GIDX(jA + 1), iA2 = GIDX(jA + 2), iA3 = GIDX(jA + 3);
            u32x4 A0 = {0, 0, 0, 0}, A1 = {0, 0, 0, 0}, A2 = {0, 0, 0, 0}, A3 = {0, 0, 0, 0};
            if (iA0 >= 0) A0 = *(const u32x4*)(hsl + ((size_t)iA0 << 7));
            if (iA1 >= 0) A1 = *(const u32x4*)(hsl + ((size_t)iA1 << 7));
            if (iA2 >= 0) A2 = *(const u32x4*)(hsl + ((size_t)iA2 << 7));
            if (iA3 >= 0) A3 = *(const u32x4*)(hsl + ((size_t)iA3 << 7));
            int jB = jA + 4;
            int iB0 = GIDX(jB + 0), iB1 = GIDX(jB + 1), iB2 = GIDX(jB + 2), iB3 = GIDX(jB + 3);

            while (__any(jA < ee)) {
                u32x4 B0 = {0, 0, 0, 0}, B1v = {0, 0, 0, 0}, B2v = {0, 0, 0, 0}, B3v = {0, 0, 0, 0};
                if (iB0 >= 0) B0  = *(const u32x4*)(hsl + ((size_t)iB0 << 7));
                if (iB1 >= 0) B1v = *(const u32x4*)(hsl + ((size_t)iB1 << 7));
                if (iB2 >= 0) B2v = *(const u32x4*)(hsl + ((size_t)iB2 << 7));
                if (iB3 >= 0) B3v = *(const u32x4*)(hsl + ((size_t)iB3 << 7));
                int jC = jB + 4;
                int iC0 = GIDX(jC + 0), iC1 = GIDX(jC + 1), iC2 = GIDX(jC + 2), iC3 = GIDX(jC + 3);
                acc_fp8x16(a, A0);
                acc_fp8x16(a, A1);
                acc_fp8x16(a, A2);
                acc_fp8x16(a, A3);
                jA = jB; A0 = B0; A1 = B1v; A2 = B2v; A3 = B3v;
                jB = jC; iB0 = iC0; iB1 = iC1; iB2 = iC2; iB3 = iC3;
            }
#undef GIDX

            if (nv) {
                u32x4 o0, o1;
#pragma unroll
                for (int j = 0; j < 4; ++j) {
                    unsigned lo0 = f2bf(a[2 * j]     * di);
                    unsigned hi0 = f2bf(a[2 * j + 1] * di);
                    o0[j] = lo0 | (hi0 << 16);
                    unsigned lo1 = f2bf(a[8 + 2 * j]     * di);
                    unsigned hi1 = f2bf(a[8 + 2 * j + 1] * di);
                    o1[j] = lo1 | (hi1 << 16);
                }
                unsigned short* mp = p.mbuf + ((size_t)nd << 7) + li * 16;
                *(u32x4*)(mp)     = o0;
                *(u32x4*)(mp + 8) = o1;
            }
        }
        gsync(p.gbar, nb, epoch);   // after aggregate

        // ---- MLP + LN ----
        for (int t = bid; t < tiles32; t += nb) {
            int r0 = t * 32;

            // load m tile: 512 chunks of 16 B
#pragma unroll
            for (int cc = 0; cc < 2; ++cc) {
                int c = tid + cc * 256;
                int row = c >> 4, colc = (c & 15) * 8;
                int grow = r0 + row;
                u32x4 v = {0, 0, 0, 0};
                if (grow < N) v = *(const u32x4*)(p.mbuf + ((size_t)grow << 7) + colc);
                *(u32x4*)(&M[row][colc]) = v;
            }
            __syncthreads();

            // prefetch residual
            unsigned short hvr[2][2][4];
#pragma unroll
            for (int rt = 0; rt < 2; ++rt) {
#pragma unroll
                for (int c = 0; c < 2; ++c) {
                    int col = cs + c * 16 + l16;
#pragma unroll
                    for (int reg = 0; reg < 4; ++reg) {
                        int grow = r0 + rt * 16 + quad * 4 + reg;
                        hvr[rt][c][reg] = (grow < N) ? hin[((size_t)grow << 7) + col] : (unsigned short)0;
                    }
                }
            }

            // GEMM1: relu(m @ W1 + b1)
            f32x4 ac1[2][2];
            ac1[0][0] = (f32x4){0.f, 0.f, 0.f, 0.f}; ac1[0][1] = (f32x4){0.f, 0.f, 0.f, 0.f};
            ac1[1][0] = (f32x4){0.f, 0.f, 0.f, 0.f}; ac1[1][1] = (f32x4){0.f, 0.f, 0.f, 0.f};
#pragma unroll
            for (int k0 = 0; k0 < 128; k0 += 32) {
                s16x8 b0 = *(const s16x8*)(W1t + ((size_t)(cs + l16) << 7) + quad * 8 + k0);
                s16x8 b1 = *(const s16x8*)(W1t + ((size_t)(cs + 16 + l16) << 7) + quad * 8 + k0);
                s16x8 a0 = *(const s16x8*)(&M[l16][quad * 8 + k0]);
                s16x8 a1 = *(const s16x8*)(&M[16 + l16][quad * 8 + k0]);
                ac1[0][0] = __builtin_amdgcn_mfma_f32_16x16x32_bf16(a0, b0, ac1[0][0], 0, 0, 0);
                ac1[0][1] = __builtin_amdgcn_mfma_f32_16x16x32_bf16(a0, b1, ac1[0][1], 0, 0, 0);
                ac1[1][0] = __builtin_amdgcn_mfma_f32_16x16x32_bf16(a1, b0, ac1[1][0], 0, 0, 0);
                ac1[1][1] = __builtin_amdgcn_mfma_f32_16x16x32_bf16(a1, b1, ac1[1][1], 0, 0, 0);
            }
#pragma unroll
            for (int rt = 0; rt < 2; ++rt) {
#pragma unroll
                for (int c = 0; c < 2; ++c) {
                    int col = cs + c * 16 + l16;
                    float bv = B1[col];
#pragma unroll
                    for (int reg = 0; reg < 4; ++reg) {
                        float v = fmaxf(ac1[rt][c][reg] + bv, 0.f);
                        P[rt * 16 + quad * 4 + reg][col] = f2bf(v);
                    }
                }
            }
            __syncthreads();

            // GEMM2: P @ W2
            f32x4 ac2[2][2];
            ac2[0][0] = (f32x4){0.f, 0.f, 0.f, 0.f}; ac2[0][1] = (f32x4){0.f, 0.f, 0.f, 0.f};
            ac2[1][0] = (f32x4){0.f, 0.f, 0.f, 0.f}; ac2[1][1] = (f32x4){0.f, 0.f, 0.f, 0.f};
#pragma unroll
            for (int k0 = 0; k0 < 128; k0 += 32) {
                s16x8 b0 = *(const s16x8*)(W2t + ((size_t)(cs + l16) << 7) + quad * 8 + k0);
                s16x8 b1 = *(const s16x8*)(W2t + ((size_t)(cs + 16 + l16) << 7) + quad * 8 + k0);
                s16x8 a0 = *(const s16x8*)(&P[l16][quad * 8 + k0]);
                s16x8 a1 = *(const s16x8*)(&P[16 + l16][quad * 8 + k0]);
                ac2[0][0] = __builtin_amdgcn_mfma_f32_16x16x32_bf16(a0, b0, ac2[0][0], 0, 0, 0);
                ac2[0][1] = __builtin_amdgcn_mfma_f32_16x16x32_bf16(a0, b1, ac2[0][1], 0, 0, 0);
                ac2[1][0] = __builtin_amdgcn_mfma_f32_16x16x32_bf16(a1, b0, ac2[1][0], 0, 0, 0);
                ac2[1][1] = __builtin_amdgcn_mfma_f32_16x16x32_bf16(a1, b1, ac2[1][1], 0, 0, 0);
            }

            // epilogue: residual + LN
            float z[2][2][4];
            float ps1[2][4] = {{0, 0, 0, 0}, {0, 0, 0, 0}};
            float ps2[2][4] = {{0, 0, 0, 0}, {0, 0, 0, 0}};
#pragma unroll
            for (int rt = 0; rt < 2; ++rt) {
#pragma unroll
                for (int c = 0; c < 2; ++c) {
                    int col = cs + c * 16 + l16;
                    float b2v = B2[col];
#pragma unroll
                    for (int reg = 0; reg < 4; ++reg) {
                        float hv = bf2f(hvr[rt][c][reg]);
                        float zz = ac2[rt][c][reg] + b2v + hv;
                        z[rt][c][reg] = zz;
                        ps1[rt][reg] += zz;
                        ps2[rt][reg] += zz * zz;
                    }
                }
            }
#pragma unroll
            for (int off = 1; off < 16; off <<= 1) {
#pragma unroll
                for (int rt = 0; rt < 2; ++rt) {
#pragma unroll
                    for (int reg = 0; reg < 4; ++reg) {
                        ps1[rt][reg] += __shfl_xor(ps1[rt][reg], off, 64);
                        ps2[rt][reg] += __shfl_xor(ps2[rt][reg], off, 64);
                    }
                }
            }
            if (l16 == 0) {
#pragma unroll
                for (int rt = 0; rt < 2; ++rt) {
#pragma unroll
                    for (int reg = 0; reg < 4; ++reg) {
                        s1p[wv][rt * 16 + quad * 4 + reg] = ps1[rt][reg];
                        s2p[wv][rt * 16 + quad * 4 + reg] = ps2[rt][reg];
                    }
                }
            }
            __syncthreads();

#pragma unroll
            for (int rt = 0; rt < 2; ++rt) {
#pragma unroll
                for (int reg = 0; reg < 4; ++reg) {
                    int row = rt * 16 + quad * 4 + reg;
                    float S1 = s1p[0][row] + s1p[1][row] + s1p[2][row] + s1p[3][row];
                    float S2 = s2p[0][row] + s2p[1][row] + s2p[2][row] + s2p[3][row];
                    float mean = S1 * (1.0f / 128.0f);
                    float var = S2 * (1.0f / 128.0f) - mean * mean;
                    float rs = rsqrtf(var + LN_EPS);
                    int grow = r0 + row;
                    if (grow < N) {
#pragma unroll
                        for (int c = 0; c < 2; ++c) {
                            int col = cs + c * 16 + l16;
                            float o = (z[rt][c][reg] - mean) * rs * G[col] + Bb[col];
                            if (out_f32) {
                                out_f32[((size_t)grow << 7) + col] = o;   // last layer: f32 only
                            } else {
                                hout[((size_t)grow << 7) + col] = f2bf(o);
                                h8out[((size_t)grow << 7) + col] = f2fp8(o);
                            }
                        }
                    }
                }
            }
            __syncthreads();   // protect M/P for next tile iteration
        }
        if (l != L - 1) gsync(p.gbar, nb, epoch);   // before next layer's gather

        unsigned short* th = hin; hin = hout; hout = th;
        unsigned char* t8 = h8in; h8in = h8out; h8out = t8;
    }
}

// ---------------- launch ----------------

extern "C" void kernel_launch(void* const* d_in, const int* in_sizes, int n_in,
                              void* d_out, int out_size, void* d_ws, size_t ws_size,
                              hipStream_t stream) {
    const float* x    = (const float*)d_in[0];
    const int*   ei   = (const int*)d_in[1];
    const float* in_w = (const float*)d_in[2];
    const float* in_b = (const float*)d_in[3];
    const float* w1   = (const float*)d_in[4];
    const float* b1   = (const float*)d_in[5];
    const float* w2   = (const float*)d_in[6];
    const float* b2   = (const float*)d_in[7];
    const float* ln_g = (const float*)d_in[8];
    const float* ln_b = (const float*)d_in[9];

    const int N = in_sizes[0] / DIM;               // 50000
    const int E = in_sizes[1] / 2;                 // 640000
    const int LAYERS = in_sizes[4] / (DIM * DIM);  // 3

    // workspace layout: gbar immediately before counts -> one memset zeroes both
    char* ws = (char*)d_ws;
    int*            gbar   = (int*)ws;             ws += 64;
    int*            counts = (int*)ws;             ws += (size_t)N * 4;
    int*            rowptr = (int*)ws;             ws += (size_t)(N + 1) * 4;
    int*            cursor = (int*)ws;             ws += (size_t)N * 4;
    float*          dinv   = (float*)ws;           ws += (size_t)N * 4;
    int*            srcidx = (int*)ws;             ws += (size_t)E * 4;
    int*            bsum   = (int*)ws;             ws += 4096;
    int*            bofs   = (int*)ws;             ws += 4096;
    unsigned short* wt     = (unsigned short*)ws;  ws += (size_t)(2 * LAYERS + 1) * DIM * DIM * 2;
    unsigned short* hb0    = (unsigned short*)ws;  ws += (size_t)N * DIM * 2;
    unsigned short* hb1    = (unsigned short*)ws;  ws += (size_t)N * DIM * 2;
    unsigned char*  h8a    = (unsigned char*)ws;   ws += (size_t)N * DIM;
    unsigned char*  h8b    = (unsigned char*)ws;   ws += (size_t)N * DIM;
    unsigned short* mbuf   = (unsigned short*)ws;  ws += (size_t)N * DIM * 2;

    // zero barrier + degree counts in one dispatch
    (void)hipMemsetAsync(gbar, 0, 64 + (size_t)N * 4, stream);

    GParams p;
    p.x = x; p.e_src = ei; p.e_dst = ei + E;
    p.in_w = in_w; p.in_b = in_b;
    p.w1 = w1; p.b1 = b1; p.w2 = w2; p.b2 = b2;
    p.ln_g = ln_g; p.ln_b = ln_b;
    p.out = (float*)d_out;
    p.hb0 = hb0; p.hb1 = hb1; p.h8a = h8a; p.h8b = h8b;
    p.gbar = gbar; p.counts = counts; p.rowptr = rowptr; p.cursor = cursor; p.dinv = dinv;
    p.srcidx = srcidx; p.bsum = bsum; p.bofs = bofs;
    p.wt = wt; p.mbuf = mbuf;
    p.N = N; p.E = E; p.L = LAYERS;

    // co-resident grid: occupancy cap (cached), <= 784 (keeps layer tiles ~2/block)
    static int nblk = 0;
    if (nblk == 0) {
        int per_cu = 0;
        hipError_t err = hipOccupancyMaxActiveBlocksPerMultiprocessor(&per_cu, gearnet_all, 256, 0);
        if (err != hipSuccess || per_cu < 1) per_cu = 1;
        int cus = 256;
        hipDeviceProp_t prop;
        int dev = 0;
        if (hipGetDevice(&dev) == hipSuccess && hipGetDeviceProperties(&prop, dev) == hipSuccess)
            cus = prop.multiProcessorCount;
        long cap = (long)per_cu * cus;
        nblk = (int)(cap < 784 ? cap : 784);
        if (nblk < 64) nblk = 64;   // safety floor (co-residency always holds at >=1/CU)
    }

    gearnet_all<<<nblk, 256, 0, stream>>>(p);
}

// Round 6
// 362.157 us; speedup vs baseline: 4.1400x; 4.1400x over previous
//
#include <hip/hip_runtime.h>
#include <hip/hip_fp8.h>

#define DIM 128
#define LN_EPS 1e-5f

typedef __attribute__((ext_vector_type(8))) short s16x8;   // 8 bf16 in 4 VGPRs
typedef __attribute__((ext_vector_type(4))) float f32x4;
typedef __attribute__((ext_vector_type(2))) float f32x2;
typedef __attribute__((ext_vector_type(4))) unsigned int u32x4;
typedef __attribute__((ext_vector_type(2))) unsigned int u32x2;

__device__ __forceinline__ unsigned short f2bf(float f) {
    unsigned u = __float_as_uint(f);
    unsigned r = u + 0x7fffu + ((u >> 16) & 1u);   // round-to-nearest-even
    return (unsigned short)(r >> 16);
}
__device__ __forceinline__ float bf2f(unsigned short b) {
    return __uint_as_float(((unsigned)b) << 16);
}
__device__ __forceinline__ unsigned char f2fp8(float f) {
    return (unsigned char)__hip_cvt_float_to_fp8(f, __HIP_SATFINITE, __HIP_E4M3);
}
// accumulate 4 fp8 bytes (linear col order) into a[0..3]
__device__ __forceinline__ void acc_fp8x4(float* a, unsigned v) {
    f32x2 lo = __builtin_amdgcn_cvt_pk_f32_fp8(v, false);  // bytes 0,1
    f32x2 hi = __builtin_amdgcn_cvt_pk_f32_fp8(v, true);   // bytes 2,3
    a[0] += lo[0]; a[1] += lo[1]; a[2] += hi[0]; a[3] += hi[1];
}
// accumulate a full u32x4 (16 fp8 bytes) into a[0..15]
__device__ __forceinline__ void acc_fp8x16(float* a, u32x4 v) {
    acc_fp8x4(a + 0,  v[0]);
    acc_fp8x4(a + 4,  v[1]);
    acc_fp8x4(a + 8,  v[2]);
    acc_fp8x4(a + 12, v[3]);
}

// fp8 plane layout: plane p (cols p*64 .. p*64+63) lives at h8[p*N*64 + row*64 + (col&63)]
__device__ __forceinline__ size_t h8addr(int col, int row, int N) {
    return (size_t)(col >> 6) * ((size_t)N * 64) + ((size_t)row << 6) + (col & 63);
}

// ---------------- prep: weight cvt (f32 -> bf16 transposed) + degree count ----------------
// blocks [0, nWblk): weights (8 blocks/matrix). blocks [nWblk, ...): count_deg.

__global__ __launch_bounds__(256) void prep(const float* __restrict__ in_w,
                                            const float* __restrict__ w1,
                                            const float* __restrict__ w2,
                                            unsigned short* __restrict__ wt, int L,
                                            const int* __restrict__ dst, int E,
                                            int* __restrict__ counts, int nWblk) {
    if ((int)blockIdx.x < nWblk) {
        int mat = blockIdx.x >> 3, part = blockIdx.x & 7;
        const float* src;
        if (mat == 0) src = in_w;
        else if (mat <= L) src = w1 + (size_t)(mat - 1) * DIM * DIM;
        else src = w2 + (size_t)(mat - 1 - L) * DIM * DIM;
        unsigned short* dstw = wt + (size_t)mat * DIM * DIM;
        int base = part * 2048 + threadIdx.x;
#pragma unroll
        for (int j = 0; j < 8; ++j) {
            int i = base + j * 256;
            int k = i >> 7, n = i & 127;
            dstw[n * DIM + k] = f2bf(src[i]);
        }
    } else {
        int b = blockIdx.x - nWblk;
        int i = (b * 256 + threadIdx.x) * 4;
        if (i + 3 < E) {
            int4 d = *(const int4*)(dst + i);
            atomicAdd(&counts[d.x], 1);
            atomicAdd(&counts[d.y], 1);
            atomicAdd(&counts[d.z], 1);
            atomicAdd(&counts[d.w], 1);
        } else {
            for (int j = i; j < E; ++j) atomicAdd(&counts[dst[j]], 1);
        }
    }
}

// --- scan step 1: per-block partial sums (1024 elems / block of 256) ---
__global__ __launch_bounds__(256) void scan_partials(const int* __restrict__ counts, int n,
                                                     int* __restrict__ bsum) {
    int base = blockIdx.x * 1024 + threadIdx.x * 4;
    int s = 0;
#pragma unroll
    for (int j = 0; j < 4; ++j) {
        int i = base + j;
        if (i < n) s += counts[i];
    }
#pragma unroll
    for (int off = 32; off > 0; off >>= 1) s += __shfl_xor(s, off, 64);
    __shared__ int wsum[4];
    int lane = threadIdx.x & 63, wid = threadIdx.x >> 6;
    if (lane == 0) wsum[wid] = s;
    __syncthreads();
    if (threadIdx.x == 0) bsum[blockIdx.x] = wsum[0] + wsum[1] + wsum[2] + wsum[3];
}

// --- scan step 2: per-block scan; block offset computed in-block from bsum ---
__global__ __launch_bounds__(256) void scan_final(const int* __restrict__ counts, int n,
                                                  const int* __restrict__ bsum, int nScan,
                                                  int* __restrict__ rowptr,
                                                  int* __restrict__ cursor,
                                                  float* __restrict__ dinv, int E) {
    __shared__ int s_bofs;
    __shared__ int wsum[4];
    int tid = threadIdx.x;
    int lane = tid & 63, wid = tid >> 6;

    if (tid < 64) {
        int acc = 0;
        for (int i = lane; i < (int)blockIdx.x; i += 64) acc += bsum[i];
#pragma unroll
        for (int off = 32; off > 0; off >>= 1) acc += __shfl_xor(acc, off, 64);
        if (lane == 0) s_bofs = acc;
    }
    if (blockIdx.x == 0 && tid == 0) rowptr[n] = E;

    int base = blockIdx.x * 1024 + tid * 4;
    int v[4];
#pragma unroll
    for (int j = 0; j < 4; ++j) {
        int i = base + j;
        v[j] = (i < n) ? counts[i] : 0;
    }
    int tsum = v[0] + v[1] + v[2] + v[3];
    int incl = tsum;
#pragma unroll
    for (int off = 1; off < 64; off <<= 1) {
        int t = __shfl_up(incl, off, 64);
        if (lane >= off) incl += t;
    }
    if (lane == 63) wsum[wid] = incl;
    __syncthreads();
    int wofs = 0;
    for (int w = 0; w < 4; ++w)
        if (w < wid) wofs += wsum[w];
    int excl = s_bofs + wofs + (incl - tsum);
#pragma unroll
    for (int j = 0; j < 4; ++j) {
        int i = base + j;
        if (i < n) {
            rowptr[i] = excl;
            cursor[i] = excl;
            dinv[i] = 1.0f / (float)((v[j] > 1) ? v[j] : 1);
            excl += v[j];
        }
    }
}

__global__ void fill_csr(const int* __restrict__ src, const int* __restrict__ dst, int E,
                         int* __restrict__ cursor, int* __restrict__ srcidx) {
    int i = (blockIdx.x * 256 + threadIdx.x) * 4;
    if (i + 3 < E) {
        int4 s = *(const int4*)(src + i);
        int4 d = *(const int4*)(dst + i);
        int p0 = atomicAdd(&cursor[d.x], 1); srcidx[p0] = s.x;
        int p1 = atomicAdd(&cursor[d.y], 1); srcidx[p1] = s.y;
        int p2 = atomicAdd(&cursor[d.z], 1); srcidx[p2] = s.z;
        int p3 = atomicAdd(&cursor[d.w], 1); srcidx[p3] = s.w;
    } else {
        for (int j = i; j < E; ++j) {
            int p = atomicAdd(&cursor[dst[j]], 1);
            srcidx[p] = src[j];
        }
    }
}

// ---------------- input projection (MFMA, col-split): hb/h8 = x @ in_w + in_b ----

__global__ __launch_bounds__(256) void gemm_bias_mfma(const float* __restrict__ x,
                                                      const unsigned short* __restrict__ Wt,
                                                      const float* __restrict__ bias,
                                                      unsigned short* __restrict__ hb,
                                                      unsigned char* __restrict__ h8, int N) {
    int tid = threadIdx.x;
    int s = tid >> 6, lane = tid & 63;
    int quad = lane >> 4, l16 = lane & 15;
    int r0 = blockIdx.x * 16;
    int cs = s * 32;
    int arow = r0 + l16;
    bool av = arow < N;

    f32x4 acc[2];
    acc[0] = (f32x4){0.f, 0.f, 0.f, 0.f};
    acc[1] = (f32x4){0.f, 0.f, 0.f, 0.f};

    const float4* xp = (const float4*)(x + ((size_t)(av ? arow : 0) << 7)) + quad * 2;
#pragma unroll
    for (int k0 = 0; k0 < 128; k0 += 32) {
        s16x8 a = {0, 0, 0, 0, 0, 0, 0, 0};
        if (av) {
            float4 f0 = xp[k0 / 4];
            float4 f1 = xp[k0 / 4 + 1];
            a[0] = (short)f2bf(f0.x); a[1] = (short)f2bf(f0.y);
            a[2] = (short)f2bf(f0.z); a[3] = (short)f2bf(f0.w);
            a[4] = (short)f2bf(f1.x); a[5] = (short)f2bf(f1.y);
            a[6] = (short)f2bf(f1.z); a[7] = (short)f2bf(f1.w);
        }
        s16x8 b0 = *(const s16x8*)(Wt + ((size_t)(cs + l16) << 7) + quad * 8 + k0);
        s16x8 b1 = *(const s16x8*)(Wt + ((size_t)(cs + 16 + l16) << 7) + quad * 8 + k0);
        acc[0] = __builtin_amdgcn_mfma_f32_16x16x32_bf16(a, b0, acc[0], 0, 0, 0);
        acc[1] = __builtin_amdgcn_mfma_f32_16x16x32_bf16(a, b1, acc[1], 0, 0, 0);
    }

#pragma unroll
    for (int c = 0; c < 2; ++c) {
        int col = cs + c * 16 + l16;
        float bv = bias[col];
#pragma unroll
        for (int reg = 0; reg < 4; ++reg) {
            int grow = r0 + quad * 4 + reg;
            if (grow < N) {
                float o = acc[c][reg] + bv;
                hb[((size_t)grow << 7) + col] = f2bf(o);
                h8[h8addr(col, grow, N)] = f2fp8(o);
            }
        }
    }
}

// ---------------- aggregation (per-plane) ----------------
// One dispatch per 64-col plane: the plane is 3.2 MB -> resident in each XCD's
// 4 MB L2 for the whole dispatch (no thrash with the other plane). block = 256
// threads = 4 independent waves; wave handles 16 nodes: 4 lanes/node, 16 B/lane
// = full 64-B plane row per edge, coalesced. 2-deep pipeline, batch 4.

__global__ __launch_bounds__(256) void aggregate(const unsigned char* __restrict__ h8plane,
                                                 const int* __restrict__ rowptr,
                                                 const int* __restrict__ srcidx,
                                                 const float* __restrict__ dinv,
                                                 unsigned short* __restrict__ mout,
                                                 int N, int plane) {
    int tid = threadIdx.x;
    int w = tid >> 6, lane = tid & 63;
    int g = lane >> 2, li = lane & 3;          // 16 nodes/wave, 4 lanes/node
    int nd = blockIdx.x * 64 + w * 16 + g;
    bool nv = nd < N;

    int e  = nv ? rowptr[nd] : 0;
    int ee = nv ? rowptr[nd + 1] : 0;
    float di = nv ? dinv[nd] : 0.f;

    const unsigned char* hsl = h8plane + li * 16;   // lane's 16-B slice of the 64-B row

    float a[16];
#pragma unroll
    for (int j = 0; j < 16; ++j) a[j] = 0.f;

#define GIDX(jj) (((jj) < ee) ? srcidx[(jj)] : -1)
    int jA = e;
    int iA0 = GIDX(jA + 0), iA1 = GIDX(jA + 1), iA2 = GIDX(jA + 2), iA3 = GIDX(jA + 3);
    u32x4 A0 = {0, 0, 0, 0}, A1 = {0, 0, 0, 0}, A2 = {0, 0, 0, 0}, A3 = {0, 0, 0, 0};
    if (iA0 >= 0) A0 = *(const u32x4*)(hsl + ((size_t)iA0 << 6));
    if (iA1 >= 0) A1 = *(const u32x4*)(hsl + ((size_t)iA1 << 6));
    if (iA2 >= 0) A2 = *(const u32x4*)(hsl + ((size_t)iA2 << 6));
    if (iA3 >= 0) A3 = *(const u32x4*)(hsl + ((size_t)iA3 << 6));
    int jB = jA + 4;
    int iB0 = GIDX(jB + 0), iB1 = GIDX(jB + 1), iB2 = GIDX(jB + 2), iB3 = GIDX(jB + 3);

    while (__any(jA < ee)) {
        u32x4 B0 = {0, 0, 0, 0}, B1v = {0, 0, 0, 0}, B2v = {0, 0, 0, 0}, B3 = {0, 0, 0, 0};
        if (iB0 >= 0) B0  = *(const u32x4*)(hsl + ((size_t)iB0 << 6));
        if (iB1 >= 0) B1v = *(const u32x4*)(hsl + ((size_t)iB1 << 6));
        if (iB2 >= 0) B2v = *(const u32x4*)(hsl + ((size_t)iB2 << 6));
        if (iB3 >= 0) B3  = *(const u32x4*)(hsl + ((size_t)iB3 << 6));
        int jC = jB + 4;
        int iC0 = GIDX(jC + 0), iC1 = GIDX(jC + 1), iC2 = GIDX(jC + 2), iC3 = GIDX(jC + 3);
        acc_fp8x16(a, A0);
        acc_fp8x16(a, A1);
        acc_fp8x16(a, A2);
        acc_fp8x16(a, A3);
        jA = jB; A0 = B0; A1 = B1v; A2 = B2v; A3 = B3;
        jB = jC; iB0 = iC0; iB1 = iC1; iB2 = iC2; iB3 = iC3;
    }
#undef GIDX

    if (nv) {
        u32x4 o0, o1;
#pragma unroll
        for (int j = 0; j < 4; ++j) {
            unsigned lo0 = f2bf(a[2 * j]     * di);
            unsigned hi0 = f2bf(a[2 * j + 1] * di);
            o0[j] = lo0 | (hi0 << 16);
            unsigned lo1 = f2bf(a[8 + 2 * j]     * di);
            unsigned hi1 = f2bf(a[8 + 2 * j + 1] * di);
            o1[j] = lo1 | (hi1 << 16);
        }
        unsigned short* mp = mout + ((size_t)nd << 7) + plane * 64 + li * 16;
        *(u32x4*)(mp)     = o0;
        *(u32x4*)(mp + 8) = o1;
    }
}

// ---------------- MLP + LN kernel (dense, streaming) ----------------

__global__ __launch_bounds__(256) void mlp_ln(const unsigned short* __restrict__ hin,
                                              const unsigned short* __restrict__ m,
                                              const unsigned short* __restrict__ W1t,
                                              const float* __restrict__ B1,
                                              const unsigned short* __restrict__ W2t,
                                              const float* __restrict__ B2,
                                              const float* __restrict__ G,
                                              const float* __restrict__ Bb,
                                              unsigned short* __restrict__ hout,
                                              unsigned char* __restrict__ h8out,
                                              float* __restrict__ out_f32, int N) {
    __shared__ unsigned short M[32][132];   // +4 pad: conflict-light b128 A-frag reads
    __shared__ unsigned short P[32][132];
    __shared__ float s1p[4][32], s2p[4][32];

    int tid = threadIdx.x;
    int w = tid >> 6, lane = tid & 63;
    int quad = lane >> 4, l16 = lane & 15;
    int r0 = blockIdx.x * 32;
    int cs = w * 32;

    // ---- load m tile: 512 chunks of 16 B (8 bf16) ----
#pragma unroll
    for (int cc = 0; cc < 2; ++cc) {
        int c = tid + cc * 256;
        int row = c >> 4, colc = (c & 15) * 8;
        int grow = r0 + row;
        u32x4 v = {0, 0, 0, 0};
        if (grow < N) v = *(const u32x4*)(m + ((size_t)grow << 7) + colc);
        *(u32x4*)(&M[row][colc]) = v;
    }
    __syncthreads();

    // ---- prefetch residual (used after GEMM2; covered by both GEMMs) ----
    unsigned short hvr[2][2][4];
#pragma unroll
    for (int rt = 0; rt < 2; ++rt) {
#pragma unroll
        for (int c = 0; c < 2; ++c) {
            int col = cs + c * 16 + l16;
#pragma unroll
            for (int reg = 0; reg < 4; ++reg) {
                int grow = r0 + rt * 16 + quad * 4 + reg;
                hvr[rt][c][reg] = (grow < N) ? hin[((size_t)grow << 7) + col] : (unsigned short)0;
            }
        }
    }

    // ---- GEMM1: relu(m @ W1 + b1); wave: 32 rows x 32 cols, B-frags shared ----
    f32x4 ac1[2][2];
    ac1[0][0] = (f32x4){0.f, 0.f, 0.f, 0.f}; ac1[0][1] = (f32x4){0.f, 0.f, 0.f, 0.f};
    ac1[1][0] = (f32x4){0.f, 0.f, 0.f, 0.f}; ac1[1][1] = (f32x4){0.f, 0.f, 0.f, 0.f};
#pragma unroll
    for (int k0 = 0; k0 < 128; k0 += 32) {
        s16x8 b0 = *(const s16x8*)(W1t + ((size_t)(cs + l16) << 7) + quad * 8 + k0);
        s16x8 b1 = *(const s16x8*)(W1t + ((size_t)(cs + 16 + l16) << 7) + quad * 8 + k0);
        s16x8 a0 = *(const s16x8*)(&M[l16][quad * 8 + k0]);
        s16x8 a1 = *(const s16x8*)(&M[16 + l16][quad * 8 + k0]);
        ac1[0][0] = __builtin_amdgcn_mfma_f32_16x16x32_bf16(a0, b0, ac1[0][0], 0, 0, 0);
        ac1[0][1] = __builtin_amdgcn_mfma_f32_16x16x32_bf16(a0, b1, ac1[0][1], 0, 0, 0);
        ac1[1][0] = __builtin_amdgcn_mfma_f32_16x16x32_bf16(a1, b0, ac1[1][0], 0, 0, 0);
        ac1[1][1] = __builtin_amdgcn_mfma_f32_16x16x32_bf16(a1, b1, ac1[1][1], 0, 0, 0);
    }
#pragma unroll
    for (int rt = 0; rt < 2; ++rt) {
#pragma unroll
        for (int c = 0; c < 2; ++c) {
            int col = cs + c * 16 + l16;
            float bv = B1[col];
#pragma unroll
            for (int reg = 0; reg < 4; ++reg) {
                float v = fmaxf(ac1[rt][c][reg] + bv, 0.f);
                P[rt * 16 + quad * 4 + reg][col] = f2bf(v);
            }
        }
    }
    __syncthreads();

    // ---- GEMM2: P @ W2 ----
    f32x4 ac2[2][2];
    ac2[0][0] = (f32x4){0.f, 0.f, 0.f, 0.f}; ac2[0][1] = (f32x4){0.f, 0.f, 0.f, 0.f};
    ac2[1][0] = (f32x4){0.f, 0.f, 0.f, 0.f}; ac2[1][1] = (f32x4){0.f, 0.f, 0.f, 0.f};
#pragma unroll
    for (int k0 = 0; k0 < 128; k0 += 32) {
        s16x8 b0 = *(const s16x8*)(W2t + ((size_t)(cs + l16) << 7) + quad * 8 + k0);
        s16x8 b1 = *(const s16x8*)(W2t + ((size_t)(cs + 16 + l16) << 7) + quad * 8 + k0);
        s16x8 a0 = *(const s16x8*)(&P[l16][quad * 8 + k0]);
        s16x8 a1 = *(const s16x8*)(&P[16 + l16][quad * 8 + k0]);
        ac2[0][0] = __builtin_amdgcn_mfma_f32_16x16x32_bf16(a0, b0, ac2[0][0], 0, 0, 0);
        ac2[0][1] = __builtin_amdgcn_mfma_f32_16x16x32_bf16(a0, b1, ac2[0][1], 0, 0, 0);
        ac2[1][0] = __builtin_amdgcn_mfma_f32_16x16x32_bf16(a1, b0, ac2[1][0], 0, 0, 0);
        ac2[1][1] = __builtin_amdgcn_mfma_f32_16x16x32_bf16(a1, b1, ac2[1][1], 0, 0, 0);
    }

    // ---- epilogue: residual + LN (cross-wave row sums via LDS partials) ----
    float z[2][2][4];
    float ps1[2][4] = {{0, 0, 0, 0}, {0, 0, 0, 0}};
    float ps2[2][4] = {{0, 0, 0, 0}, {0, 0, 0, 0}};
#pragma unroll
    for (int rt = 0; rt < 2; ++rt) {
#pragma unroll
        for (int c = 0; c < 2; ++c) {
            int col = cs + c * 16 + l16;
            float b2v = B2[col];
#pragma unroll
            for (int reg = 0; reg < 4; ++reg) {
                float hv = bf2f(hvr[rt][c][reg]);
                float zz = ac2[rt][c][reg] + b2v + hv;
                z[rt][c][reg] = zz;
                ps1[rt][reg] += zz;
                ps2[rt][reg] += zz * zz;
            }
        }
    }
#pragma unroll
    for (int off = 1; off < 16; off <<= 1) {
#pragma unroll
        for (int rt = 0; rt < 2; ++rt) {
#pragma unroll
            for (int reg = 0; reg < 4; ++reg) {
                ps1[rt][reg] += __shfl_xor(ps1[rt][reg], off, 64);
                ps2[rt][reg] += __shfl_xor(ps2[rt][reg], off, 64);
            }
        }
    }
    if (l16 == 0) {
#pragma unroll
        for (int rt = 0; rt < 2; ++rt) {
#pragma unroll
            for (int reg = 0; reg < 4; ++reg) {
                s1p[w][rt * 16 + quad * 4 + reg] = ps1[rt][reg];
                s2p[w][rt * 16 + quad * 4 + reg] = ps2[rt][reg];
            }
        }
    }
    __syncthreads();

#pragma unroll
    for (int rt = 0; rt < 2; ++rt) {
#pragma unroll
        for (int reg = 0; reg < 4; ++reg) {
            int row = rt * 16 + quad * 4 + reg;
            float S1 = s1p[0][row] + s1p[1][row] + s1p[2][row] + s1p[3][row];
            float S2 = s2p[0][row] + s2p[1][row] + s2p[2][row] + s2p[3][row];
            float mean = S1 * (1.0f / 128.0f);
            float var = S2 * (1.0f / 128.0f) - mean * mean;
            float rs = rsqrtf(var + LN_EPS);
            int grow = r0 + row;
            if (grow < N) {
#pragma unroll
                for (int c = 0; c < 2; ++c) {
                    int col = cs + c * 16 + l16;
                    float o = (z[rt][c][reg] - mean) * rs * G[col] + Bb[col];
                    if (out_f32) {
                        out_f32[((size_t)grow << 7) + col] = o;   // last layer: f32 only
                    } else {
                        hout[((size_t)grow << 7) + col] = f2bf(o);
                        h8out[h8addr(col, grow, N)] = f2fp8(o);
                    }
                }
            }
        }
    }
}

// ---------------- launch ----------------

extern "C" void kernel_launch(void* const* d_in, const int* in_sizes, int n_in,
                              void* d_out, int out_size, void* d_ws, size_t ws_size,
                              hipStream_t stream) {
    const float* x    = (const float*)d_in[0];
    const int*   ei   = (const int*)d_in[1];
    const float* in_w = (const float*)d_in[2];
    const float* in_b = (const float*)d_in[3];
    const float* w1   = (const float*)d_in[4];
    const float* b1   = (const float*)d_in[5];
    const float* w2   = (const float*)d_in[6];
    const float* b2   = (const float*)d_in[7];
    const float* ln_g = (const float*)d_in[8];
    const float* ln_b = (const float*)d_in[9];

    const int N = in_sizes[0] / DIM;               // 50000
    const int E = in_sizes[1] / 2;                 // 640000
    const int LAYERS = in_sizes[4] / (DIM * DIM);  // 3

    const int* e_src = ei;
    const int* e_dst = ei + E;

    // workspace layout
    char* ws = (char*)d_ws;
    unsigned short* hb0    = (unsigned short*)ws;  ws += (size_t)N * DIM * 2;
    unsigned short* hb1    = (unsigned short*)ws;  ws += (size_t)N * DIM * 2;
    unsigned char*  h8a    = (unsigned char*)ws;   ws += (size_t)N * DIM;   // 2 planes of N*64
    unsigned char*  h8b    = (unsigned char*)ws;   ws += (size_t)N * DIM;   // 2 planes of N*64
    int*            counts = (int*)ws;             ws += (size_t)N * 4;
    int*            rowptr = (int*)ws;             ws += (size_t)(N + 1) * 4;
    int*            cursor = (int*)ws;             ws += (size_t)N * 4;
    float*          dinv   = (float*)ws;           ws += (size_t)N * 4;
    int*            srcidx = (int*)ws;             ws += (size_t)E * 4;
    int*            bsum   = (int*)ws;             ws += 4096;
    unsigned short* wt     = (unsigned short*)ws;  ws += (size_t)(2 * LAYERS + 1) * DIM * DIM * 2;
    unsigned short* mbuf   = (unsigned short*)ws;  ws += (size_t)N * DIM * 2;

    const int nScanBlocks = (N + 1023) / 1024;
    const int nMat = 2 * LAYERS + 1;
    const int nWblk = nMat * 8;

    // --- CSR build (deg is layer-invariant) + weight conversion ---
    (void)hipMemsetAsync(counts, 0, (size_t)N * 4, stream);
    prep<<<nWblk + (E + 1023) / 1024, 256, 0, stream>>>(in_w, w1, w2, wt, LAYERS,
                                                        e_dst, E, counts, nWblk);
    scan_partials<<<nScanBlocks, 256, 0, stream>>>(counts, N, bsum);
    scan_final<<<nScanBlocks, 256, 0, stream>>>(counts, N, bsum, nScanBlocks,
                                                rowptr, cursor, dinv, E);
    fill_csr<<<(E + 1023) / 1024, 256, 0, stream>>>(e_src, e_dst, E, cursor, srcidx);

    const unsigned short* in_wt = wt;
    const unsigned short* w1t   = wt + (size_t)DIM * DIM;
    const unsigned short* w2t   = wt + (size_t)(1 + LAYERS) * DIM * DIM;

    // --- input projection ---
    gemm_bias_mfma<<<(N + 15) / 16, 256, 0, stream>>>(x, in_wt, in_b, hb0, h8a, N);

    // --- layers (ping-pong; gather reads pre-update fp8 planes) ---
    int agg_grid = (N + 63) / 64;
    int mlp_grid = (N + 31) / 32;
    unsigned short* hin  = hb0;  unsigned char* h8in  = h8a;
    unsigned short* hout = hb1;  unsigned char* h8out = h8b;
    for (int i = 0; i < LAYERS; ++i) {
        float* out = (i == LAYERS - 1) ? (float*)d_out : nullptr;
        // per-plane aggregation: each dispatch's gather working set is 3.2 MB
        // (fits per-XCD 4 MB L2); dispatch boundary keeps planes phase-separated.
        aggregate<<<agg_grid, 256, 0, stream>>>(h8in, rowptr, srcidx, dinv, mbuf, N, 0);
        aggregate<<<agg_grid, 256, 0, stream>>>(h8in + (size_t)N * 64, rowptr, srcidx, dinv,
                                                mbuf, N, 1);
        mlp_ln<<<mlp_grid, 256, 0, stream>>>(hin, mbuf,
                                             w1t + (size_t)i * DIM * DIM, b1 + (size_t)i * DIM,
                                             w2t + (size_t)i * DIM * DIM, b2 + (size_t)i * DIM,
                                             ln_g + (size_t)i * DIM, ln_b + (size_t)i * DIM,
                                             hout, h8out, out, N);
        unsigned short* t = hin; hin = hout; hout = t;
        unsigned char* t8 = h8in; h8in = h8out; h8out = t8;
    }
}

// Round 7
// 330.285 us; speedup vs baseline: 4.5395x; 1.0965x over previous
//
#include <hip/hip_runtime.h>
#include <hip/hip_fp8.h>

#define DIM 128
#define LN_EPS 1e-5f

typedef __attribute__((ext_vector_type(8))) short s16x8;   // 8 bf16 in 4 VGPRs
typedef __attribute__((ext_vector_type(4))) float f32x4;
typedef __attribute__((ext_vector_type(2))) float f32x2;
typedef __attribute__((ext_vector_type(4))) unsigned int u32x4;

__device__ __forceinline__ unsigned short f2bf(float f) {
    unsigned u = __float_as_uint(f);
    unsigned r = u + 0x7fffu + ((u >> 16) & 1u);   // round-to-nearest-even
    return (unsigned short)(r >> 16);
}
__device__ __forceinline__ float bf2f(unsigned short b) {
    return __uint_as_float(((unsigned)b) << 16);
}
__device__ __forceinline__ unsigned char f2fp8(float f) {
    return (unsigned char)__hip_cvt_float_to_fp8(f, __HIP_SATFINITE, __HIP_E4M3);
}
// accumulate 4 fp8 bytes (linear col order) into a[0..3]
__device__ __forceinline__ void acc_fp8x4(float* a, unsigned v) {
    f32x2 lo = __builtin_amdgcn_cvt_pk_f32_fp8(v, false);  // bytes 0,1
    f32x2 hi = __builtin_amdgcn_cvt_pk_f32_fp8(v, true);   // bytes 2,3
    a[0] += lo[0]; a[1] += lo[1]; a[2] += hi[0]; a[3] += hi[1];
}
// accumulate a full u32x4 (16 fp8 bytes) into a[0..15]
__device__ __forceinline__ void acc_fp8x16(float* a, u32x4 v) {
    acc_fp8x4(a + 0,  v[0]);
    acc_fp8x4(a + 4,  v[1]);
    acc_fp8x4(a + 8,  v[2]);
    acc_fp8x4(a + 12, v[3]);
}

// ---------------- prep: weight cvt (f32 -> bf16 transposed) + degree count ----------------
// blocks [0, nWblk): weights (8 blocks/matrix). blocks [nWblk, ...): count_deg.

__global__ __launch_bounds__(256) void prep(const float* __restrict__ in_w,
                                            const float* __restrict__ w1,
                                            const float* __restrict__ w2,
                                            unsigned short* __restrict__ wt, int L,
                                            const int* __restrict__ dst, int E,
                                            int* __restrict__ counts, int nWblk) {
    if ((int)blockIdx.x < nWblk) {
        int mat = blockIdx.x >> 3, part = blockIdx.x & 7;
        const float* src;
        if (mat == 0) src = in_w;
        else if (mat <= L) src = w1 + (size_t)(mat - 1) * DIM * DIM;
        else src = w2 + (size_t)(mat - 1 - L) * DIM * DIM;
        unsigned short* dstw = wt + (size_t)mat * DIM * DIM;
        int base = part * 2048 + threadIdx.x;
#pragma unroll
        for (int j = 0; j < 8; ++j) {
            int i = base + j * 256;
            int k = i >> 7, n = i & 127;
            dstw[n * DIM + k] = f2bf(src[i]);
        }
    } else {
        int b = blockIdx.x - nWblk;
        int i = (b * 256 + threadIdx.x) * 4;
        if (i + 3 < E) {
            int4 d = *(const int4*)(dst + i);
            atomicAdd(&counts[d.x], 1);
            atomicAdd(&counts[d.y], 1);
            atomicAdd(&counts[d.z], 1);
            atomicAdd(&counts[d.w], 1);
        } else {
            for (int j = i; j < E; ++j) atomicAdd(&counts[dst[j]], 1);
        }
    }
}

// ---------------- scan (single dispatch): block offset computed in-block ----------------
// Block b sums counts[0 .. b*1024) directly (L2-resident, <=192 KB), then does the
// in-block exclusive scan and emits rowptr/cursor/dinv.

__global__ __launch_bounds__(256) void scan_all(const int* __restrict__ counts, int n,
                                                int* __restrict__ rowptr,
                                                int* __restrict__ cursor,
                                                float* __restrict__ dinv, int E) {
    __shared__ int wsum[4];
    int tid = threadIdx.x;
    int lane = tid & 63, wid = tid >> 6;

    // ---- block offset: sum of all counts before this block's range ----
    int limit = blockIdx.x * 1024;            // multiple of 1024
    int acc = 0;
    for (int i = tid * 4; i < limit; i += 1024) {
        int4 c4 = *(const int4*)(counts + i); // i+3 < limit (limit % 1024 == 0)
        acc += c4.x + c4.y + c4.z + c4.w;
    }
#pragma unroll
    for (int off = 32; off > 0; off >>= 1) acc += __shfl_xor(acc, off, 64);
    if (lane == 0) wsum[wid] = acc;
    __syncthreads();
    int bofs = wsum[0] + wsum[1] + wsum[2] + wsum[3];
    __syncthreads();                          // wsum reused below

    if (blockIdx.x == 0 && tid == 0) rowptr[n] = E;

    // ---- in-block exclusive scan of 1024 counts ----
    int base = blockIdx.x * 1024 + tid * 4;
    int v[4];
#pragma unroll
    for (int j = 0; j < 4; ++j) {
        int i = base + j;
        v[j] = (i < n) ? counts[i] : 0;
    }
    int tsum = v[0] + v[1] + v[2] + v[3];
    int incl = tsum;
#pragma unroll
    for (int off = 1; off < 64; off <<= 1) {
        int t = __shfl_up(incl, off, 64);
        if (lane >= off) incl += t;
    }
    if (lane == 63) wsum[wid] = incl;
    __syncthreads();
    int wofs = 0;
    for (int w = 0; w < 4; ++w)
        if (w < wid) wofs += wsum[w];
    int excl = bofs + wofs + (incl - tsum);
#pragma unroll
    for (int j = 0; j < 4; ++j) {
        int i = base + j;
        if (i < n) {
            rowptr[i] = excl;
            cursor[i] = excl;
            dinv[i] = 1.0f / (float)((v[j] > 1) ? v[j] : 1);
            excl += v[j];
        }
    }
}

// ---------------- fused: input projection + CSR fill (independent work) -------------
// blocks [0, gemmBlocks): hb/h8 = x @ in_w + in_b (MFMA col-split, 16 rows/block).
// blocks [gemmBlocks, ...): fill_csr (4 edges/thread). Both must complete before
// layer 0 — same dispatch boundary.

__global__ __launch_bounds__(256) void fill_proj(const float* __restrict__ x,
                                                 const unsigned short* __restrict__ Wt,
                                                 const float* __restrict__ bias,
                                                 unsigned short* __restrict__ hb,
                                                 unsigned char* __restrict__ h8, int N,
                                                 const int* __restrict__ src,
                                                 const int* __restrict__ dst, int E,
                                                 int* __restrict__ cursor,
                                                 int* __restrict__ srcidx, int gemmBlocks) {
    int tid = threadIdx.x;
    if ((int)blockIdx.x < gemmBlocks) {
        int s = tid >> 6, lane = tid & 63;
        int quad = lane >> 4, l16 = lane & 15;
        int r0 = blockIdx.x * 16;
        int cs = s * 32;
        int arow = r0 + l16;
        bool av = arow < N;

        f32x4 acc0 = (f32x4){0.f, 0.f, 0.f, 0.f};
        f32x4 acc1 = (f32x4){0.f, 0.f, 0.f, 0.f};

        const float4* xp = (const float4*)(x + ((size_t)(av ? arow : 0) << 7)) + quad * 2;
#pragma unroll
        for (int k0 = 0; k0 < 128; k0 += 32) {
            s16x8 a = {0, 0, 0, 0, 0, 0, 0, 0};
            if (av) {
                float4 f0 = xp[k0 / 4];
                float4 f1 = xp[k0 / 4 + 1];
                a[0] = (short)f2bf(f0.x); a[1] = (short)f2bf(f0.y);
                a[2] = (short)f2bf(f0.z); a[3] = (short)f2bf(f0.w);
                a[4] = (short)f2bf(f1.x); a[5] = (short)f2bf(f1.y);
                a[6] = (short)f2bf(f1.z); a[7] = (short)f2bf(f1.w);
            }
            s16x8 b0 = *(const s16x8*)(Wt + ((size_t)(cs + l16) << 7) + quad * 8 + k0);
            s16x8 b1 = *(const s16x8*)(Wt + ((size_t)(cs + 16 + l16) << 7) + quad * 8 + k0);
            acc0 = __builtin_amdgcn_mfma_f32_16x16x32_bf16(a, b0, acc0, 0, 0, 0);
            acc1 = __builtin_amdgcn_mfma_f32_16x16x32_bf16(a, b1, acc1, 0, 0, 0);
        }

#pragma unroll
        for (int c = 0; c < 2; ++c) {
            int col = cs + c * 16 + l16;
            float bv = bias[col];
#pragma unroll
            for (int reg = 0; reg < 4; ++reg) {
                int grow = r0 + quad * 4 + reg;
                if (grow < N) {
                    float o = (c == 0 ? acc0[reg] : acc1[reg]) + bv;
                    hb[((size_t)grow << 7) + col] = f2bf(o);
                    h8[((size_t)grow << 7) + col] = f2fp8(o);
                }
            }
        }
    } else {
        int b = blockIdx.x - gemmBlocks;
        int i = (b * 256 + tid) * 4;
        if (i + 3 < E) {
            int4 s4 = *(const int4*)(src + i);
            int4 d4 = *(const int4*)(dst + i);
            int p0 = atomicAdd(&cursor[d4.x], 1); srcidx[p0] = s4.x;
            int p1 = atomicAdd(&cursor[d4.y], 1); srcidx[p1] = s4.y;
            int p2 = atomicAdd(&cursor[d4.z], 1); srcidx[p2] = s4.z;
            int p3 = atomicAdd(&cursor[d4.w], 1); srcidx[p3] = s4.w;
        } else {
            for (int j = i; j < E; ++j) {
                int p = atomicAdd(&cursor[dst[j]], 1);
                srcidx[p] = src[j];
            }
        }
    }
}

// ---------------- aggregation-only kernel (round-4 form) ----------------
// block = 256 threads = 4 independent waves (no LDS, no barriers). Wave handles
// 8 nodes: 8 lanes/node, 16 B/lane = full 128-B fp8 row per edge, coalesced.
// 2-deep software pipeline, batch 4. Output m = (sum of neighbor rows) * dinv.

__global__ __launch_bounds__(256) void aggregate(const unsigned char* __restrict__ h8in,
                                                 const int* __restrict__ rowptr,
                                                 const int* __restrict__ srcidx,
                                                 const float* __restrict__ dinv,
                                                 unsigned short* __restrict__ mout, int N) {
    int tid = threadIdx.x;
    int w = tid >> 6, lane = tid & 63;
    int g = lane >> 3, li = lane & 7;
    int nd = blockIdx.x * 32 + w * 8 + g;
    bool nv = nd < N;

    int e  = nv ? rowptr[nd] : 0;
    int ee = nv ? rowptr[nd + 1] : 0;
    float di = nv ? dinv[nd] : 0.f;

    const unsigned char* hsl = h8in + li * 16;   // lane's 16-B slice of a row

    float a[16];
#pragma unroll
    for (int j = 0; j < 16; ++j) a[j] = 0.f;

#define GIDX(jj) (((jj) < ee) ? srcidx[(jj)] : -1)
    int jA = e;
    int iA0 = GIDX(jA + 0), iA1 = GIDX(jA + 1), iA2 = GIDX(jA + 2), iA3 = GIDX(jA + 3);
    u32x4 A0 = {0, 0, 0, 0}, A1 = {0, 0, 0, 0}, A2 = {0, 0, 0, 0}, A3 = {0, 0, 0, 0};
    if (iA0 >= 0) A0 = *(const u32x4*)(hsl + ((size_t)iA0 << 7));
    if (iA1 >= 0) A1 = *(const u32x4*)(hsl + ((size_t)iA1 << 7));
    if (iA2 >= 0) A2 = *(const u32x4*)(hsl + ((size_t)iA2 << 7));
    if (iA3 >= 0) A3 = *(const u32x4*)(hsl + ((size_t)iA3 << 7));
    int jB = jA + 4;
    int iB0 = GIDX(jB + 0), iB1 = GIDX(jB + 1), iB2 = GIDX(jB + 2), iB3 = GIDX(jB + 3);

    while (__any(jA < ee)) {
        u32x4 B0 = {0, 0, 0, 0}, B1v = {0, 0, 0, 0}, B2v = {0, 0, 0, 0}, B3 = {0, 0, 0, 0};
        if (iB0 >= 0) B0  = *(const u32x4*)(hsl + ((size_t)iB0 << 7));
        if (iB1 >= 0) B1v = *(const u32x4*)(hsl + ((size_t)iB1 << 7));
        if (iB2 >= 0) B2v = *(const u32x4*)(hsl + ((size_t)iB2 << 7));
        if (iB3 >= 0) B3  = *(const u32x4*)(hsl + ((size_t)iB3 << 7));
        int jC = jB + 4;
        int iC0 = GIDX(jC + 0), iC1 = GIDX(jC + 1), iC2 = GIDX(jC + 2), iC3 = GIDX(jC + 3);
        acc_fp8x16(a, A0);
        acc_fp8x16(a, A1);
        acc_fp8x16(a, A2);
        acc_fp8x16(a, A3);
        jA = jB; A0 = B0; A1 = B1v; A2 = B2v; A3 = B3;
        jB = jC; iB0 = iC0; iB1 = iC1; iB2 = iC2; iB3 = iC3;
    }
#undef GIDX

    if (nv) {
        u32x4 o0, o1;
#pragma unroll
        for (int j = 0; j < 4; ++j) {
            unsigned lo0 = f2bf(a[2 * j]     * di);
            unsigned hi0 = f2bf(a[2 * j + 1] * di);
            o0[j] = lo0 | (hi0 << 16);
            unsigned lo1 = f2bf(a[8 + 2 * j]     * di);
            unsigned hi1 = f2bf(a[8 + 2 * j + 1] * di);
            o1[j] = lo1 | (hi1 << 16);
        }
        unsigned short* mp = mout + ((size_t)nd << 7) + li * 16;
        *(u32x4*)(mp)     = o0;
        *(u32x4*)(mp + 8) = o1;
    }
}

// ---------------- MLP + LN kernel (dense, streaming; round-4 form) ----------------

__global__ __launch_bounds__(256) void mlp_ln(const unsigned short* __restrict__ hin,
                                              const unsigned short* __restrict__ m,
                                              const unsigned short* __restrict__ W1t,
                                              const float* __restrict__ B1,
                                              const unsigned short* __restrict__ W2t,
                                              const float* __restrict__ B2,
                                              const float* __restrict__ G,
                                              const float* __restrict__ Bb,
                                              unsigned short* __restrict__ hout,
                                              unsigned char* __restrict__ h8out,
                                              float* __restrict__ out_f32, int N) {
    __shared__ unsigned short M[32][132];   // +4 pad: conflict-light b128 A-frag reads
    __shared__ unsigned short P[32][132];
    __shared__ float s1p[4][32], s2p[4][32];

    int tid = threadIdx.x;
    int w = tid >> 6, lane = tid & 63;
    int quad = lane >> 4, l16 = lane & 15;
    int r0 = blockIdx.x * 32;
    int cs = w * 32;

    // ---- load m tile: 512 chunks of 16 B (8 bf16) ----
#pragma unroll
    for (int cc = 0; cc < 2; ++cc) {
        int c = tid + cc * 256;
        int row = c >> 4, colc = (c & 15) * 8;
        int grow = r0 + row;
        u32x4 v = {0, 0, 0, 0};
        if (grow < N) v = *(const u32x4*)(m + ((size_t)grow << 7) + colc);
        *(u32x4*)(&M[row][colc]) = v;
    }
    __syncthreads();

    // ---- prefetch residual (used after GEMM2; covered by both GEMMs) ----
    unsigned short hvr[2][2][4];
#pragma unroll
    for (int rt = 0; rt < 2; ++rt) {
#pragma unroll
        for (int c = 0; c < 2; ++c) {
            int col = cs + c * 16 + l16;
#pragma unroll
            for (int reg = 0; reg < 4; ++reg) {
                int grow = r0 + rt * 16 + quad * 4 + reg;
                hvr[rt][c][reg] = (grow < N) ? hin[((size_t)grow << 7) + col] : (unsigned short)0;
            }
        }
    }

    // ---- GEMM1: relu(m @ W1 + b1); wave: 32 rows x 32 cols, B-frags shared ----
    f32x4 ac1[2][2];
    ac1[0][0] = (f32x4){0.f, 0.f, 0.f, 0.f}; ac1[0][1] = (f32x4){0.f, 0.f, 0.f, 0.f};
    ac1[1][0] = (f32x4){0.f, 0.f, 0.f, 0.f}; ac1[1][1] = (f32x4){0.f, 0.f, 0.f, 0.f};
#pragma unroll
    for (int k0 = 0; k0 < 128; k0 += 32) {
        s16x8 b0 = *(const s16x8*)(W1t + ((size_t)(cs + l16) << 7) + quad * 8 + k0);
        s16x8 b1 = *(const s16x8*)(W1t + ((size_t)(cs + 16 + l16) << 7) + quad * 8 + k0);
        s16x8 a0 = *(const s16x8*)(&M[l16][quad * 8 + k0]);
        s16x8 a1 = *(const s16x8*)(&M[16 + l16][quad * 8 + k0]);
        ac1[0][0] = __builtin_amdgcn_mfma_f32_16x16x32_bf16(a0, b0, ac1[0][0], 0, 0, 0);
        ac1[0][1] = __builtin_amdgcn_mfma_f32_16x16x32_bf16(a0, b1, ac1[0][1], 0, 0, 0);
        ac1[1][0] = __builtin_amdgcn_mfma_f32_16x16x32_bf16(a1, b0, ac1[1][0], 0, 0, 0);
        ac1[1][1] = __builtin_amdgcn_mfma_f32_16x16x32_bf16(a1, b1, ac1[1][1], 0, 0, 0);
    }
#pragma unroll
    for (int rt = 0; rt < 2; ++rt) {
#pragma unroll
        for (int c = 0; c < 2; ++c) {
            int col = cs + c * 16 + l16;
            float bv = B1[col];
#pragma unroll
            for (int reg = 0; reg < 4; ++reg) {
                float v = fmaxf(ac1[rt][c][reg] + bv, 0.f);
                P[rt * 16 + quad * 4 + reg][col] = f2bf(v);
            }
        }
    }
    __syncthreads();

    // ---- GEMM2: P @ W2 ----
    f32x4 ac2[2][2];
    ac2[0][0] = (f32x4){0.f, 0.f, 0.f, 0.f}; ac2[0][1] = (f32x4){0.f, 0.f, 0.f, 0.f};
    ac2[1][0] = (f32x4){0.f, 0.f, 0.f, 0.f}; ac2[1][1] = (f32x4){0.f, 0.f, 0.f, 0.f};
#pragma unroll
    for (int k0 = 0; k0 < 128; k0 += 32) {
        s16x8 b0 = *(const s16x8*)(W2t + ((size_t)(cs + l16) << 7) + quad * 8 + k0);
        s16x8 b1 = *(const s16x8*)(W2t + ((size_t)(cs + 16 + l16) << 7) + quad * 8 + k0);
        s16x8 a0 = *(const s16x8*)(&P[l16][quad * 8 + k0]);
        s16x8 a1 = *(const s16x8*)(&P[16 + l16][quad * 8 + k0]);
        ac2[0][0] = __builtin_amdgcn_mfma_f32_16x16x32_bf16(a0, b0, ac2[0][0], 0, 0, 0);
        ac2[0][1] = __builtin_amdgcn_mfma_f32_16x16x32_bf16(a0, b1, ac2[0][1], 0, 0, 0);
        ac2[1][0] = __builtin_amdgcn_mfma_f32_16x16x32_bf16(a1, b0, ac2[1][0], 0, 0, 0);
        ac2[1][1] = __builtin_amdgcn_mfma_f32_16x16x32_bf16(a1, b1, ac2[1][1], 0, 0, 0);
    }

    // ---- epilogue: residual + LN (cross-wave row sums via LDS partials) ----
    float z[2][2][4];
    float ps1[2][4] = {{0, 0, 0, 0}, {0, 0, 0, 0}};
    float ps2[2][4] = {{0, 0, 0, 0}, {0, 0, 0, 0}};
#pragma unroll
    for (int rt = 0; rt < 2; ++rt) {
#pragma unroll
        for (int c = 0; c < 2; ++c) {
            int col = cs + c * 16 + l16;
            float b2v = B2[col];
#pragma unroll
            for (int reg = 0; reg < 4; ++reg) {
                float hv = bf2f(hvr[rt][c][reg]);
                float zz = ac2[rt][c][reg] + b2v + hv;
                z[rt][c][reg] = zz;
                ps1[rt][reg] += zz;
                ps2[rt][reg] += zz * zz;
            }
        }
    }
#pragma unroll
    for (int off = 1; off < 16; off <<= 1) {
#pragma unroll
        for (int rt = 0; rt < 2; ++rt) {
#pragma unroll
            for (int reg = 0; reg < 4; ++reg) {
                ps1[rt][reg] += __shfl_xor(ps1[rt][reg], off, 64);
                ps2[rt][reg] += __shfl_xor(ps2[rt][reg], off, 64);
            }
        }
    }
    if (l16 == 0) {
#pragma unroll
        for (int rt = 0; rt < 2; ++rt) {
#pragma unroll
            for (int reg = 0; reg < 4; ++reg) {
                s1p[w][rt * 16 + quad * 4 + reg] = ps1[rt][reg];
                s2p[w][rt * 16 + quad * 4 + reg] = ps2[rt][reg];
            }
        }
    }
    __syncthreads();

#pragma unroll
    for (int rt = 0; rt < 2; ++rt) {
#pragma unroll
        for (int reg = 0; reg < 4; ++reg) {
            int row = rt * 16 + quad * 4 + reg;
            float S1 = s1p[0][row] + s1p[1][row] + s1p[2][row] + s1p[3][row];
            float S2 = s2p[0][row] + s2p[1][row] + s2p[2][row] + s2p[3][row];
            float mean = S1 * (1.0f / 128.0f);
            float var = S2 * (1.0f / 128.0f) - mean * mean;
            float rs = rsqrtf(var + LN_EPS);
            int grow = r0 + row;
            if (grow < N) {
#pragma unroll
                for (int c = 0; c < 2; ++c) {
                    int col = cs + c * 16 + l16;
                    float o = (z[rt][c][reg] - mean) * rs * G[col] + Bb[col];
                    if (out_f32) {
                        out_f32[((size_t)grow << 7) + col] = o;   // last layer: f32 only
                    } else {
                        hout[((size_t)grow << 7) + col] = f2bf(o);
                        h8out[((size_t)grow << 7) + col] = f2fp8(o);
                    }
                }
            }
        }
    }
}

// ---------------- launch ----------------

extern "C" void kernel_launch(void* const* d_in, const int* in_sizes, int n_in,
                              void* d_out, int out_size, void* d_ws, size_t ws_size,
                              hipStream_t stream) {
    const float* x    = (const float*)d_in[0];
    const int*   ei   = (const int*)d_in[1];
    const float* in_w = (const float*)d_in[2];
    const float* in_b = (const float*)d_in[3];
    const float* w1   = (const float*)d_in[4];
    const float* b1   = (const float*)d_in[5];
    const float* w2   = (const float*)d_in[6];
    const float* b2   = (const float*)d_in[7];
    const float* ln_g = (const float*)d_in[8];
    const float* ln_b = (const float*)d_in[9];

    const int N = in_sizes[0] / DIM;               // 50000
    const int E = in_sizes[1] / 2;                 // 640000
    const int LAYERS = in_sizes[4] / (DIM * DIM);  // 3

    const int* e_src = ei;
    const int* e_dst = ei + E;

    // workspace layout
    char* ws = (char*)d_ws;
    unsigned short* hb0    = (unsigned short*)ws;  ws += (size_t)N * DIM * 2;
    unsigned short* hb1    = (unsigned short*)ws;  ws += (size_t)N * DIM * 2;
    unsigned char*  h8a    = (unsigned char*)ws;   ws += (size_t)N * DIM;
    unsigned char*  h8b    = (unsigned char*)ws;   ws += (size_t)N * DIM;
    int*            counts = (int*)ws;             ws += (size_t)N * 4;
    int*            rowptr = (int*)ws;             ws += (size_t)(N + 1) * 4;
    int*            cursor = (int*)ws;             ws += (size_t)N * 4;
    float*          dinv   = (float*)ws;           ws += (size_t)N * 4;
    int*            srcidx = (int*)ws;             ws += (size_t)E * 4;
    unsigned short* wt     = (unsigned short*)ws;  ws += (size_t)(2 * LAYERS + 1) * DIM * DIM * 2;
    unsigned short* mbuf   = (unsigned short*)ws;  ws += (size_t)N * DIM * 2;

    const int nScanBlocks = (N + 1023) / 1024;
    const int nMat = 2 * LAYERS + 1;
    const int nWblk = nMat * 8;
    const int gemmBlocks = (N + 15) / 16;
    const int fillBlocks = (E + 1023) / 1024;

    // --- CSR build + weight cvt + input projection: 4 dispatches total ---
    (void)hipMemsetAsync(counts, 0, (size_t)N * 4, stream);
    prep<<<nWblk + (E + 1023) / 1024, 256, 0, stream>>>(in_w, w1, w2, wt, LAYERS,
                                                        e_dst, E, counts, nWblk);
    scan_all<<<nScanBlocks, 256, 0, stream>>>(counts, N, rowptr, cursor, dinv, E);
    fill_proj<<<gemmBlocks + fillBlocks, 256, 0, stream>>>(x, wt, in_b, hb0, h8a, N,
                                                           e_src, e_dst, E, cursor, srcidx,
                                                           gemmBlocks);

    const unsigned short* w1t = wt + (size_t)DIM * DIM;
    const unsigned short* w2t = wt + (size_t)(1 + LAYERS) * DIM * DIM;

    // --- layers (ping-pong; gather reads pre-update fp8 table) ---
    int tile_grid = (N + 31) / 32;
    unsigned short* hin  = hb0;  unsigned char* h8in  = h8a;
    unsigned short* hout = hb1;  unsigned char* h8out = h8b;
    for (int i = 0; i < LAYERS; ++i) {
        float* out = (i == LAYERS - 1) ? (float*)d_out : nullptr;
        aggregate<<<tile_grid, 256, 0, stream>>>(h8in, rowptr, srcidx, dinv, mbuf, N);
        mlp_ln<<<tile_grid, 256, 0, stream>>>(hin, mbuf,
                                              w1t + (size_t)i * DIM * DIM, b1 + (size_t)i * DIM,
                                              w2t + (size_t)i * DIM * DIM, b2 + (size_t)i * DIM,
                                              ln_g + (size_t)i * DIM, ln_b + (size_t)i * DIM,
                                              hout, h8out, out, N);
        unsigned short* t = hin; hin = hout; hout = t;
        unsigned char* t8 = h8in; h8in = h8out; h8out = t8;
    }
}

// Round 8
// 322.052 us; speedup vs baseline: 4.6555x; 1.0256x over previous
//
#include <hip/hip_runtime.h>
#include <hip/hip_fp8.h>

#define DIM 128
#define LN_EPS 1e-5f

typedef __attribute__((ext_vector_type(8))) short s16x8;   // 8 bf16 in 4 VGPRs
typedef __attribute__((ext_vector_type(4))) float f32x4;
typedef __attribute__((ext_vector_type(2))) float f32x2;
typedef __attribute__((ext_vector_type(4))) unsigned int u32x4;

__device__ __forceinline__ unsigned short f2bf(float f) {
    unsigned u = __float_as_uint(f);
    unsigned r = u + 0x7fffu + ((u >> 16) & 1u);   // round-to-nearest-even
    return (unsigned short)(r >> 16);
}
__device__ __forceinline__ float bf2f(unsigned short b) {
    return __uint_as_float(((unsigned)b) << 16);
}
__device__ __forceinline__ unsigned char f2fp8(float f) {
    return (unsigned char)__hip_cvt_float_to_fp8(f, __HIP_SATFINITE, __HIP_E4M3);
}
// accumulate 4 fp8 bytes (linear col order) into a[0..3]
__device__ __forceinline__ void acc_fp8x4(float* a, unsigned v) {
    f32x2 lo = __builtin_amdgcn_cvt_pk_f32_fp8(v, false);  // bytes 0,1
    f32x2 hi = __builtin_amdgcn_cvt_pk_f32_fp8(v, true);   // bytes 2,3
    a[0] += lo[0]; a[1] += lo[1]; a[2] += hi[0]; a[3] += hi[1];
}
// accumulate a full u32x4 (16 fp8 bytes) into a[0..15]
__device__ __forceinline__ void acc_fp8x16(float* a, u32x4 v) {
    acc_fp8x4(a + 0,  v[0]);
    acc_fp8x4(a + 4,  v[1]);
    acc_fp8x4(a + 8,  v[2]);
    acc_fp8x4(a + 12, v[3]);
}

// ---------------- prep: weight cvt (f32 -> bf16 transposed) + degree count ----------------

__global__ __launch_bounds__(256) void prep(const float* __restrict__ in_w,
                                            const float* __restrict__ w1,
                                            const float* __restrict__ w2,
                                            unsigned short* __restrict__ wt, int L,
                                            const int* __restrict__ dst, int E,
                                            int* __restrict__ counts, int nWblk) {
    if ((int)blockIdx.x < nWblk) {
        int mat = blockIdx.x >> 3, part = blockIdx.x & 7;
        const float* src;
        if (mat == 0) src = in_w;
        else if (mat <= L) src = w1 + (size_t)(mat - 1) * DIM * DIM;
        else src = w2 + (size_t)(mat - 1 - L) * DIM * DIM;
        unsigned short* dstw = wt + (size_t)mat * DIM * DIM;
        int base = part * 2048 + threadIdx.x;
#pragma unroll
        for (int j = 0; j < 8; ++j) {
            int i = base + j * 256;
            int k = i >> 7, n = i & 127;
            dstw[n * DIM + k] = f2bf(src[i]);
        }
    } else {
        int b = blockIdx.x - nWblk;
        int i = (b * 256 + threadIdx.x) * 4;
        if (i + 3 < E) {
            int4 d = *(const int4*)(dst + i);
            atomicAdd(&counts[d.x], 1);
            atomicAdd(&counts[d.y], 1);
            atomicAdd(&counts[d.z], 1);
            atomicAdd(&counts[d.w], 1);
        } else {
            for (int j = i; j < E; ++j) atomicAdd(&counts[dst[j]], 1);
        }
    }
}

// ---------------- scan (single dispatch): block offset computed in-block ----------------

__global__ __launch_bounds__(256) void scan_all(const int* __restrict__ counts, int n,
                                                int* __restrict__ rowptr,
                                                int* __restrict__ cursor,
                                                float* __restrict__ dinv, int E) {
    __shared__ int wsum[4];
    int tid = threadIdx.x;
    int lane = tid & 63, wid = tid >> 6;

    int limit = blockIdx.x * 1024;            // multiple of 1024
    int acc = 0;
    for (int i = tid * 4; i < limit; i += 1024) {
        int4 c4 = *(const int4*)(counts + i);
        acc += c4.x + c4.y + c4.z + c4.w;
    }
#pragma unroll
    for (int off = 32; off > 0; off >>= 1) acc += __shfl_xor(acc, off, 64);
    if (lane == 0) wsum[wid] = acc;
    __syncthreads();
    int bofs = wsum[0] + wsum[1] + wsum[2] + wsum[3];
    __syncthreads();                          // wsum reused below

    if (blockIdx.x == 0 && tid == 0) rowptr[n] = E;

    int base = blockIdx.x * 1024 + tid * 4;
    int v[4];
#pragma unroll
    for (int j = 0; j < 4; ++j) {
        int i = base + j;
        v[j] = (i < n) ? counts[i] : 0;
    }
    int tsum = v[0] + v[1] + v[2] + v[3];
    int incl = tsum;
#pragma unroll
    for (int off = 1; off < 64; off <<= 1) {
        int t = __shfl_up(incl, off, 64);
        if (lane >= off) incl += t;
    }
    if (lane == 63) wsum[wid] = incl;
    __syncthreads();
    int wofs = 0;
    for (int w = 0; w < 4; ++w)
        if (w < wid) wofs += wsum[w];
    int excl = bofs + wofs + (incl - tsum);
#pragma unroll
    for (int j = 0; j < 4; ++j) {
        int i = base + j;
        if (i < n) {
            rowptr[i] = excl;
            cursor[i] = excl;
            dinv[i] = 1.0f / (float)((v[j] > 1) ? v[j] : 1);
            excl += v[j];
        }
    }
}

// ---------------- CSR fill (separate dispatch, for measurement + ushort srcidx) -----

__global__ void fill_csr(const int* __restrict__ src, const int* __restrict__ dst, int E,
                         int* __restrict__ cursor, unsigned short* __restrict__ srcidx) {
    int i = (blockIdx.x * 256 + threadIdx.x) * 4;
    if (i + 3 < E) {
        int4 s4 = *(const int4*)(src + i);
        int4 d4 = *(const int4*)(dst + i);
        int p0 = atomicAdd(&cursor[d4.x], 1); srcidx[p0] = (unsigned short)s4.x;
        int p1 = atomicAdd(&cursor[d4.y], 1); srcidx[p1] = (unsigned short)s4.y;
        int p2 = atomicAdd(&cursor[d4.z], 1); srcidx[p2] = (unsigned short)s4.z;
        int p3 = atomicAdd(&cursor[d4.w], 1); srcidx[p3] = (unsigned short)s4.w;
    } else {
        for (int j = i; j < E; ++j) {
            int p = atomicAdd(&cursor[dst[j]], 1);
            srcidx[p] = (unsigned short)src[j];
        }
    }
}

// ---------------- input projection: 32 rows/block, x staged via LDS ----------------
// Stage: each thread loads 64 B of x contiguously (fully coalesced), converts to
// bf16, stores to LDS. GEMM reads fragments from LDS (mlp_ln pattern), B-frags
// shared across the two 16-row subtiles.

__global__ __launch_bounds__(256) void gemm_bias32(const float* __restrict__ x,
                                                   const unsigned short* __restrict__ Wt,
                                                   const float* __restrict__ bias,
                                                   unsigned short* __restrict__ hb,
                                                   unsigned char* __restrict__ h8, int N) {
    __shared__ unsigned short X[32][132];

    int tid = threadIdx.x;
    int w = tid >> 6, lane = tid & 63;
    int quad = lane >> 4, l16 = lane & 15;
    int r0 = blockIdx.x * 32;
    int cs = w * 32;

    // ---- stage x tile: thread covers row (tid>>3), cols [(tid&7)*16, +16) ----
    {
        int row = tid >> 3;
        int c0 = (tid & 7) * 16;
        int grow = r0 + row;
        u32x4 o0 = {0, 0, 0, 0}, o1 = {0, 0, 0, 0};
        if (grow < N) {
            const float4* xp = (const float4*)(x + ((size_t)grow << 7) + c0);
            float4 f0 = xp[0], f1 = xp[1], f2 = xp[2], f3 = xp[3];
            o0[0] = (unsigned)f2bf(f0.x) | ((unsigned)f2bf(f0.y) << 16);
            o0[1] = (unsigned)f2bf(f0.z) | ((unsigned)f2bf(f0.w) << 16);
            o0[2] = (unsigned)f2bf(f1.x) | ((unsigned)f2bf(f1.y) << 16);
            o0[3] = (unsigned)f2bf(f1.z) | ((unsigned)f2bf(f1.w) << 16);
            o1[0] = (unsigned)f2bf(f2.x) | ((unsigned)f2bf(f2.y) << 16);
            o1[1] = (unsigned)f2bf(f2.z) | ((unsigned)f2bf(f2.w) << 16);
            o1[2] = (unsigned)f2bf(f3.x) | ((unsigned)f2bf(f3.y) << 16);
            o1[3] = (unsigned)f2bf(f3.z) | ((unsigned)f2bf(f3.w) << 16);
        }
        *(u32x4*)(&X[row][c0])     = o0;
        *(u32x4*)(&X[row][c0 + 8]) = o1;
    }
    __syncthreads();

    // ---- GEMM: wave computes 32 rows x 32 cols, B-frags shared ----
    f32x4 ac[2][2];
    ac[0][0] = (f32x4){0.f, 0.f, 0.f, 0.f}; ac[0][1] = (f32x4){0.f, 0.f, 0.f, 0.f};
    ac[1][0] = (f32x4){0.f, 0.f, 0.f, 0.f}; ac[1][1] = (f32x4){0.f, 0.f, 0.f, 0.f};
#pragma unroll
    for (int k0 = 0; k0 < 128; k0 += 32) {
        s16x8 b0 = *(const s16x8*)(Wt + ((size_t)(cs + l16) << 7) + quad * 8 + k0);
        s16x8 b1 = *(const s16x8*)(Wt + ((size_t)(cs + 16 + l16) << 7) + quad * 8 + k0);
        s16x8 a0 = *(const s16x8*)(&X[l16][quad * 8 + k0]);
        s16x8 a1 = *(const s16x8*)(&X[16 + l16][quad * 8 + k0]);
        ac[0][0] = __builtin_amdgcn_mfma_f32_16x16x32_bf16(a0, b0, ac[0][0], 0, 0, 0);
        ac[0][1] = __builtin_amdgcn_mfma_f32_16x16x32_bf16(a0, b1, ac[0][1], 0, 0, 0);
        ac[1][0] = __builtin_amdgcn_mfma_f32_16x16x32_bf16(a1, b0, ac[1][0], 0, 0, 0);
        ac[1][1] = __builtin_amdgcn_mfma_f32_16x16x32_bf16(a1, b1, ac[1][1], 0, 0, 0);
    }

#pragma unroll
    for (int rt = 0; rt < 2; ++rt) {
#pragma unroll
        for (int c = 0; c < 2; ++c) {
            int col = cs + c * 16 + l16;
            float bv = bias[col];
#pragma unroll
            for (int reg = 0; reg < 4; ++reg) {
                int grow = r0 + rt * 16 + quad * 4 + reg;
                if (grow < N) {
                    float o = ac[rt][c][reg] + bv;
                    hb[((size_t)grow << 7) + col] = f2bf(o);
                    h8[((size_t)grow << 7) + col] = f2fp8(o);
                }
            }
        }
    }
}

// ---------------- aggregation-only kernel (round-4 form, ushort srcidx) ----------------

__global__ __launch_bounds__(256) void aggregate(const unsigned char* __restrict__ h8in,
                                                 const int* __restrict__ rowptr,
                                                 const unsigned short* __restrict__ srcidx,
                                                 const float* __restrict__ dinv,
                                                 unsigned short* __restrict__ mout, int N) {
    int tid = threadIdx.x;
    int w = tid >> 6, lane = tid & 63;
    int g = lane >> 3, li = lane & 7;
    int nd = blockIdx.x * 32 + w * 8 + g;
    bool nv = nd < N;

    int e  = nv ? rowptr[nd] : 0;
    int ee = nv ? rowptr[nd + 1] : 0;
    float di = nv ? dinv[nd] : 0.f;

    const unsigned char* hsl = h8in + li * 16;   // lane's 16-B slice of a row

    float a[16];
#pragma unroll
    for (int j = 0; j < 16; ++j) a[j] = 0.f;

#define GIDX(jj) (((jj) < ee) ? (int)srcidx[(jj)] : -1)
    int jA = e;
    int iA0 = GIDX(jA + 0), iA1 = GIDX(jA + 1), iA2 = GIDX(jA + 2), iA3 = GIDX(jA + 3);
    u32x4 A0 = {0, 0, 0, 0}, A1 = {0, 0, 0, 0}, A2 = {0, 0, 0, 0}, A3 = {0, 0, 0, 0};
    if (iA0 >= 0) A0 = *(const u32x4*)(hsl + ((size_t)iA0 << 7));
    if (iA1 >= 0) A1 = *(const u32x4*)(hsl + ((size_t)iA1 << 7));
    if (iA2 >= 0) A2 = *(const u32x4*)(hsl + ((size_t)iA2 << 7));
    if (iA3 >= 0) A3 = *(const u32x4*)(hsl + ((size_t)iA3 << 7));
    int jB = jA + 4;
    int iB0 = GIDX(jB + 0), iB1 = GIDX(jB + 1), iB2 = GIDX(jB + 2), iB3 = GIDX(jB + 3);

    while (__any(jA < ee)) {
        u32x4 B0 = {0, 0, 0, 0}, B1v = {0, 0, 0, 0}, B2v = {0, 0, 0, 0}, B3 = {0, 0, 0, 0};
        if (iB0 >= 0) B0  = *(const u32x4*)(hsl + ((size_t)iB0 << 7));
        if (iB1 >= 0) B1v = *(const u32x4*)(hsl + ((size_t)iB1 << 7));
        if (iB2 >= 0) B2v = *(const u32x4*)(hsl + ((size_t)iB2 << 7));
        if (iB3 >= 0) B3  = *(const u32x4*)(hsl + ((size_t)iB3 << 7));
        int jC = jB + 4;
        int iC0 = GIDX(jC + 0), iC1 = GIDX(jC + 1), iC2 = GIDX(jC + 2), iC3 = GIDX(jC + 3);
        acc_fp8x16(a, A0);
        acc_fp8x16(a, A1);
        acc_fp8x16(a, A2);
        acc_fp8x16(a, A3);
        jA = jB; A0 = B0; A1 = B1v; A2 = B2v; A3 = B3;
        jB = jC; iB0 = iC0; iB1 = iC1; iB2 = iC2; iB3 = iC3;
    }
#undef GIDX

    if (nv) {
        u32x4 o0, o1;
#pragma unroll
        for (int j = 0; j < 4; ++j) {
            unsigned lo0 = f2bf(a[2 * j]     * di);
            unsigned hi0 = f2bf(a[2 * j + 1] * di);
            o0[j] = lo0 | (hi0 << 16);
            unsigned lo1 = f2bf(a[8 + 2 * j]     * di);
            unsigned hi1 = f2bf(a[8 + 2 * j + 1] * di);
            o1[j] = lo1 | (hi1 << 16);
        }
        unsigned short* mp = mout + ((size_t)nd << 7) + li * 16;
        *(u32x4*)(mp)     = o0;
        *(u32x4*)(mp + 8) = o1;
    }
}

// ---------------- MLP + LN kernel (dense, streaming; round-4 form) ----------------

__global__ __launch_bounds__(256) void mlp_ln(const unsigned short* __restrict__ hin,
                                              const unsigned short* __restrict__ m,
                                              const unsigned short* __restrict__ W1t,
                                              const float* __restrict__ B1,
                                              const unsigned short* __restrict__ W2t,
                                              const float* __restrict__ B2,
                                              const float* __restrict__ G,
                                              const float* __restrict__ Bb,
                                              unsigned short* __restrict__ hout,
                                              unsigned char* __restrict__ h8out,
                                              float* __restrict__ out_f32, int N) {
    __shared__ unsigned short M[32][132];   // +4 pad: conflict-light b128 A-frag reads
    __shared__ unsigned short P[32][132];
    __shared__ float s1p[4][32], s2p[4][32];

    int tid = threadIdx.x;
    int w = tid >> 6, lane = tid & 63;
    int quad = lane >> 4, l16 = lane & 15;
    int r0 = blockIdx.x * 32;
    int cs = w * 32;

    // ---- load m tile: 512 chunks of 16 B (8 bf16) ----
#pragma unroll
    for (int cc = 0; cc < 2; ++cc) {
        int c = tid + cc * 256;
        int row = c >> 4, colc = (c & 15) * 8;
        int grow = r0 + row;
        u32x4 v = {0, 0, 0, 0};
        if (grow < N) v = *(const u32x4*)(m + ((size_t)grow << 7) + colc);
        *(u32x4*)(&M[row][colc]) = v;
    }
    __syncthreads();

    // ---- prefetch residual (used after GEMM2; covered by both GEMMs) ----
    unsigned short hvr[2][2][4];
#pragma unroll
    for (int rt = 0; rt < 2; ++rt) {
#pragma unroll
        for (int c = 0; c < 2; ++c) {
            int col = cs + c * 16 + l16;
#pragma unroll
            for (int reg = 0; reg < 4; ++reg) {
                int grow = r0 + rt * 16 + quad * 4 + reg;
                hvr[rt][c][reg] = (grow < N) ? hin[((size_t)grow << 7) + col] : (unsigned short)0;
            }
        }
    }

    // ---- GEMM1: relu(m @ W1 + b1); wave: 32 rows x 32 cols, B-frags shared ----
    f32x4 ac1[2][2];
    ac1[0][0] = (f32x4){0.f, 0.f, 0.f, 0.f}; ac1[0][1] = (f32x4){0.f, 0.f, 0.f, 0.f};
    ac1[1][0] = (f32x4){0.f, 0.f, 0.f, 0.f}; ac1[1][1] = (f32x4){0.f, 0.f, 0.f, 0.f};
#pragma unroll
    for (int k0 = 0; k0 < 128; k0 += 32) {
        s16x8 b0 = *(const s16x8*)(W1t + ((size_t)(cs + l16) << 7) + quad * 8 + k0);
        s16x8 b1 = *(const s16x8*)(W1t + ((size_t)(cs + 16 + l16) << 7) + quad * 8 + k0);
        s16x8 a0 = *(const s16x8*)(&M[l16][quad * 8 + k0]);
        s16x8 a1 = *(const s16x8*)(&M[16 + l16][quad * 8 + k0]);
        ac1[0][0] = __builtin_amdgcn_mfma_f32_16x16x32_bf16(a0, b0, ac1[0][0], 0, 0, 0);
        ac1[0][1] = __builtin_amdgcn_mfma_f32_16x16x32_bf16(a0, b1, ac1[0][1], 0, 0, 0);
        ac1[1][0] = __builtin_amdgcn_mfma_f32_16x16x32_bf16(a1, b0, ac1[1][0], 0, 0, 0);
        ac1[1][1] = __builtin_amdgcn_mfma_f32_16x16x32_bf16(a1, b1, ac1[1][1], 0, 0, 0);
    }
#pragma unroll
    for (int rt = 0; rt < 2; ++rt) {
#pragma unroll
        for (int c = 0; c < 2; ++c) {
            int col = cs + c * 16 + l16;
            float bv = B1[col];
#pragma unroll
            for (int reg = 0; reg < 4; ++reg) {
                float v = fmaxf(ac1[rt][c][reg] + bv, 0.f);
                P[rt * 16 + quad * 4 + reg][col] = f2bf(v);
            }
        }
    }
    __syncthreads();

    // ---- GEMM2: P @ W2 ----
    f32x4 ac2[2][2];
    ac2[0][0] = (f32x4){0.f, 0.f, 0.f, 0.f}; ac2[0][1] = (f32x4){0.f, 0.f, 0.f, 0.f};
    ac2[1][0] = (f32x4){0.f, 0.f, 0.f, 0.f}; ac2[1][1] = (f32x4){0.f, 0.f, 0.f, 0.f};
#pragma unroll
    for (int k0 = 0; k0 < 128; k0 += 32) {
        s16x8 b0 = *(const s16x8*)(W2t + ((size_t)(cs + l16) << 7) + quad * 8 + k0);
        s16x8 b1 = *(const s16x8*)(W2t + ((size_t)(cs + 16 + l16) << 7) + quad * 8 + k0);
        s16x8 a0 = *(const s16x8*)(&P[l16][quad * 8 + k0]);
        s16x8 a1 = *(const s16x8*)(&P[16 + l16][quad * 8 + k0]);
        ac2[0][0] = __builtin_amdgcn_mfma_f32_16x16x32_bf16(a0, b0, ac2[0][0], 0, 0, 0);
        ac2[0][1] = __builtin_amdgcn_mfma_f32_16x16x32_bf16(a0, b1, ac2[0][1], 0, 0, 0);
        ac2[1][0] = __builtin_amdgcn_mfma_f32_16x16x32_bf16(a1, b0, ac2[1][0], 0, 0, 0);
        ac2[1][1] = __builtin_amdgcn_mfma_f32_16x16x32_bf16(a1, b1, ac2[1][1], 0, 0, 0);
    }

    // ---- epilogue: residual + LN (cross-wave row sums via LDS partials) ----
    float z[2][2][4];
    float ps1[2][4] = {{0, 0, 0, 0}, {0, 0, 0, 0}};
    float ps2[2][4] = {{0, 0, 0, 0}, {0, 0, 0, 0}};
#pragma unroll
    for (int rt = 0; rt < 2; ++rt) {
#pragma unroll
        for (int c = 0; c < 2; ++c) {
            int col = cs + c * 16 + l16;
            float b2v = B2[col];
#pragma unroll
            for (int reg = 0; reg < 4; ++reg) {
                float hv = bf2f(hvr[rt][c][reg]);
                float zz = ac2[rt][c][reg] + b2v + hv;
                z[rt][c][reg] = zz;
                ps1[rt][reg] += zz;
                ps2[rt][reg] += zz * zz;
            }
        }
    }
#pragma unroll
    for (int off = 1; off < 16; off <<= 1) {
#pragma unroll
        for (int rt = 0; rt < 2; ++rt) {
#pragma unroll
            for (int reg = 0; reg < 4; ++reg) {
                ps1[rt][reg] += __shfl_xor(ps1[rt][reg], off, 64);
                ps2[rt][reg] += __shfl_xor(ps2[rt][reg], off, 64);
            }
        }
    }
    if (l16 == 0) {
#pragma unroll
        for (int rt = 0; rt < 2; ++rt) {
#pragma unroll
            for (int reg = 0; reg < 4; ++reg) {
                s1p[w][rt * 16 + quad * 4 + reg] = ps1[rt][reg];
                s2p[w][rt * 16 + quad * 4 + reg] = ps2[rt][reg];
            }
        }
    }
    __syncthreads();

#pragma unroll
    for (int rt = 0; rt < 2; ++rt) {
#pragma unroll
        for (int reg = 0; reg < 4; ++reg) {
            int row = rt * 16 + quad * 4 + reg;
            float S1 = s1p[0][row] + s1p[1][row] + s1p[2][row] + s1p[3][row];
            float S2 = s2p[0][row] + s2p[1][row] + s2p[2][row] + s2p[3][row];
            float mean = S1 * (1.0f / 128.0f);
            float var = S2 * (1.0f / 128.0f) - mean * mean;
            float rs = rsqrtf(var + LN_EPS);
            int grow = r0 + row;
            if (grow < N) {
#pragma unroll
                for (int c = 0; c < 2; ++c) {
                    int col = cs + c * 16 + l16;
                    float o = (z[rt][c][reg] - mean) * rs * G[col] + Bb[col];
                    if (out_f32) {
                        out_f32[((size_t)grow << 7) + col] = o;   // last layer: f32 only
                    } else {
                        hout[((size_t)grow << 7) + col] = f2bf(o);
                        h8out[((size_t)grow << 7) + col] = f2fp8(o);
                    }
                }
            }
        }
    }
}

// ---------------- launch ----------------

extern "C" void kernel_launch(void* const* d_in, const int* in_sizes, int n_in,
                              void* d_out, int out_size, void* d_ws, size_t ws_size,
                              hipStream_t stream) {
    const float* x    = (const float*)d_in[0];
    const int*   ei   = (const int*)d_in[1];
    const float* in_w = (const float*)d_in[2];
    const float* in_b = (const float*)d_in[3];
    const float* w1   = (const float*)d_in[4];
    const float* b1   = (const float*)d_in[5];
    const float* w2   = (const float*)d_in[6];
    const float* b2   = (const float*)d_in[7];
    const float* ln_g = (const float*)d_in[8];
    const float* ln_b = (const float*)d_in[9];

    const int N = in_sizes[0] / DIM;               // 50000
    const int E = in_sizes[1] / 2;                 // 640000
    const int LAYERS = in_sizes[4] / (DIM * DIM);  // 3

    const int* e_src = ei;
    const int* e_dst = ei + E;

    // workspace layout
    char* ws = (char*)d_ws;
    unsigned short* hb0    = (unsigned short*)ws;  ws += (size_t)N * DIM * 2;
    unsigned short* hb1    = (unsigned short*)ws;  ws += (size_t)N * DIM * 2;
    unsigned char*  h8a    = (unsigned char*)ws;   ws += (size_t)N * DIM;
    unsigned char*  h8b    = (unsigned char*)ws;   ws += (size_t)N * DIM;
    int*            counts = (int*)ws;             ws += (size_t)N * 4;
    int*            rowptr = (int*)ws;             ws += (size_t)(N + 1) * 4;
    int*            cursor = (int*)ws;             ws += (size_t)N * 4;
    float*          dinv   = (float*)ws;           ws += (size_t)N * 4;
    unsigned short* srcidx = (unsigned short*)ws;  ws += (size_t)E * 2;
    unsigned short* wt     = (unsigned short*)ws;  ws += (size_t)(2 * LAYERS + 1) * DIM * DIM * 2;
    unsigned short* mbuf   = (unsigned short*)ws;  ws += (size_t)N * DIM * 2;

    const int nScanBlocks = (N + 1023) / 1024;
    const int nMat = 2 * LAYERS + 1;
    const int nWblk = nMat * 8;

    // --- CSR build + weight cvt + input projection ---
    (void)hipMemsetAsync(counts, 0, (size_t)N * 4, stream);
    prep<<<nWblk + (E + 1023) / 1024, 256, 0, stream>>>(in_w, w1, w2, wt, LAYERS,
                                                        e_dst, E, counts, nWblk);
    scan_all<<<nScanBlocks, 256, 0, stream>>>(counts, N, rowptr, cursor, dinv, E);
    gemm_bias32<<<(N + 31) / 32, 256, 0, stream>>>(x, wt, in_b, hb0, h8a, N);
    fill_csr<<<(E + 1023) / 1024, 256, 0, stream>>>(e_src, e_dst, E, cursor, srcidx);

    const unsigned short* w1t = wt + (size_t)DIM * DIM;
    const unsigned short* w2t = wt + (size_t)(1 + LAYERS) * DIM * DIM;

    // --- layers (ping-pong; gather reads pre-update fp8 table) ---
    int tile_grid = (N + 31) / 32;
    unsigned short* hin  = hb0;  unsigned char* h8in  = h8a;
    unsigned short* hout = hb1;  unsigned char* h8out = h8b;
    for (int i = 0; i < LAYERS; ++i) {
        float* out = (i == LAYERS - 1) ? (float*)d_out : nullptr;
        aggregate<<<tile_grid, 256, 0, stream>>>(h8in, rowptr, srcidx, dinv, mbuf, N);
        mlp_ln<<<tile_grid, 256, 0, stream>>>(hin, mbuf,
                                              w1t + (size_t)i * DIM * DIM, b1 + (size_t)i * DIM,
                                              w2t + (size_t)i * DIM * DIM, b2 + (size_t)i * DIM,
                                              ln_g + (size_t)i * DIM, ln_b + (size_t)i * DIM,
                                              hout, h8out, out, N);
        unsigned short* t = hin; hin = hout; hout = t;
        unsigned char* t8 = h8in; h8in = h8out; h8out = t8;
    }
}

// Round 10
// 321.643 us; speedup vs baseline: 4.6614x; 1.0013x over previous
//
#include <hip/hip_runtime.h>
#include <hip/hip_fp8.h>

#define DIM 128
#define LN_EPS 1e-5f

typedef __attribute__((ext_vector_type(8))) short s16x8;   // 8 bf16 in 4 VGPRs
typedef __attribute__((ext_vector_type(4))) float f32x4;
typedef __attribute__((ext_vector_type(2))) float f32x2;
typedef __attribute__((ext_vector_type(4))) unsigned int u32x4;

__device__ __forceinline__ unsigned short f2bf(float f) {
    unsigned u = __float_as_uint(f);
    unsigned r = u + 0x7fffu + ((u >> 16) & 1u);   // round-to-nearest-even
    return (unsigned short)(r >> 16);
}
__device__ __forceinline__ float bf2f(unsigned short b) {
    return __uint_as_float(((unsigned)b) << 16);
}
__device__ __forceinline__ unsigned char f2fp8(float f) {
    return (unsigned char)__hip_cvt_float_to_fp8(f, __HIP_SATFINITE, __HIP_E4M3);
}
// accumulate 4 fp8 bytes (linear col order) into a[0..3]
__device__ __forceinline__ void acc_fp8x4(float* a, unsigned v) {
    f32x2 lo = __builtin_amdgcn_cvt_pk_f32_fp8(v, false);  // bytes 0,1
    f32x2 hi = __builtin_amdgcn_cvt_pk_f32_fp8(v, true);   // bytes 2,3
    a[0] += lo[0]; a[1] += lo[1]; a[2] += hi[0]; a[3] += hi[1];
}
// accumulate a full u32x4 (16 fp8 bytes) into a[0..15]
__device__ __forceinline__ void acc_fp8x16(float* a, u32x4 v) {
    acc_fp8x4(a + 0,  v[0]);
    acc_fp8x4(a + 4,  v[1]);
    acc_fp8x4(a + 8,  v[2]);
    acc_fp8x4(a + 12, v[3]);
}

// ---------------- prep: weight cvt (f32 -> bf16 transposed) + degree count ----------------

__global__ __launch_bounds__(256) void prep(const float* __restrict__ in_w,
                                            const float* __restrict__ w1,
                                            const float* __restrict__ w2,
                                            unsigned short* __restrict__ wt, int L,
                                            const int* __restrict__ dst, int E,
                                            int* __restrict__ counts, int nWblk) {
    if ((int)blockIdx.x < nWblk) {
        int mat = blockIdx.x >> 3, part = blockIdx.x & 7;
        const float* src;
        if (mat == 0) src = in_w;
        else if (mat <= L) src = w1 + (size_t)(mat - 1) * DIM * DIM;
        else src = w2 + (size_t)(mat - 1 - L) * DIM * DIM;
        unsigned short* dstw = wt + (size_t)mat * DIM * DIM;
        int base = part * 2048 + threadIdx.x;
#pragma unroll
        for (int j = 0; j < 8; ++j) {
            int i = base + j * 256;
            int k = i >> 7, n = i & 127;
            dstw[n * DIM + k] = f2bf(src[i]);
        }
    } else {
        int b = blockIdx.x - nWblk;
        int i = (b * 256 + threadIdx.x) * 4;
        if (i + 3 < E) {
            int4 d = *(const int4*)(dst + i);
            atomicAdd(&counts[d.x], 1);
            atomicAdd(&counts[d.y], 1);
            atomicAdd(&counts[d.z], 1);
            atomicAdd(&counts[d.w], 1);
        } else {
            for (int j = i; j < E; ++j) atomicAdd(&counts[dst[j]], 1);
        }
    }
}

// ---------------- scan (single dispatch): block offset computed in-block ----------------

__global__ __launch_bounds__(256) void scan_all(const int* __restrict__ counts, int n,
                                                int* __restrict__ rowptr,
                                                int* __restrict__ cursor,
                                                float* __restrict__ dinv, int E) {
    __shared__ int wsum[4];
    int tid = threadIdx.x;
    int lane = tid & 63, wid = tid >> 6;

    int limit = blockIdx.x * 1024;            // multiple of 1024
    int acc = 0;
    for (int i = tid * 4; i < limit; i += 1024) {
        int4 c4 = *(const int4*)(counts + i);
        acc += c4.x + c4.y + c4.z + c4.w;
    }
#pragma unroll
    for (int off = 32; off > 0; off >>= 1) acc += __shfl_xor(acc, off, 64);
    if (lane == 0) wsum[wid] = acc;
    __syncthreads();
    int bofs = wsum[0] + wsum[1] + wsum[2] + wsum[3];
    __syncthreads();                          // wsum reused below

    if (blockIdx.x == 0 && tid == 0) rowptr[n] = E;

    int base = blockIdx.x * 1024 + tid * 4;
    int v[4];
#pragma unroll
    for (int j = 0; j < 4; ++j) {
        int i = base + j;
        v[j] = (i < n) ? counts[i] : 0;
    }
    int tsum = v[0] + v[1] + v[2] + v[3];
    int incl = tsum;
#pragma unroll
    for (int off = 1; off < 64; off <<= 1) {
        int t = __shfl_up(incl, off, 64);
        if (lane >= off) incl += t;
    }
    if (lane == 63) wsum[wid] = incl;
    __syncthreads();
    int wofs = 0;
    for (int w = 0; w < 4; ++w)
        if (w < wid) wofs += wsum[w];
    int excl = bofs + wofs + (incl - tsum);
#pragma unroll
    for (int j = 0; j < 4; ++j) {
        int i = base + j;
        if (i < n) {
            rowptr[i] = excl;
            cursor[i] = excl;
            dinv[i] = 1.0f / (float)((v[j] > 1) ? v[j] : 1);
            excl += v[j];
        }
    }
}

// ---------------- CSR fill ----------------

__global__ void fill_csr(const int* __restrict__ src, const int* __restrict__ dst, int E,
                         int* __restrict__ cursor, unsigned short* __restrict__ srcidx) {
    int i = (blockIdx.x * 256 + threadIdx.x) * 4;
    if (i + 3 < E) {
        int4 s4 = *(const int4*)(src + i);
        int4 d4 = *(const int4*)(dst + i);
        int p0 = atomicAdd(&cursor[d4.x], 1); srcidx[p0] = (unsigned short)s4.x;
        int p1 = atomicAdd(&cursor[d4.y], 1); srcidx[p1] = (unsigned short)s4.y;
        int p2 = atomicAdd(&cursor[d4.z], 1); srcidx[p2] = (unsigned short)s4.z;
        int p3 = atomicAdd(&cursor[d4.w], 1); srcidx[p3] = (unsigned short)s4.w;
    } else {
        for (int j = i; j < E; ++j) {
            int p = atomicAdd(&cursor[dst[j]], 1);
            srcidx[p] = (unsigned short)src[j];
        }
    }
}

// ---------------- input projection: 32 rows/block, LDS-transposed epilogue ----------
// BIT-EXACT vs round-8: o = ac + bias computed in f32, routed through LDS Z
// unchanged, rounded by the same f2bf/f2fp8. Only the store layout changes
// (row-contiguous 16-B vector stores instead of 24 scattered sub-word stores).
// Typed __shared__, 136-short row stride: every 16-B LDS access naturally aligned.

__global__ __launch_bounds__(256) void gemm_bias32(const float* __restrict__ x,
                                                   const unsigned short* __restrict__ Wt,
                                                   const float* __restrict__ bias,
                                                   unsigned short* __restrict__ hb,
                                                   unsigned char* __restrict__ h8, int N) {
    __shared__ __align__(16) unsigned short X[32][136];
    __shared__ __align__(16) float Z[32][132];
    __shared__ __align__(16) float bias_s[128];

    int tid = threadIdx.x;
    int w = tid >> 6, lane = tid & 63;
    int quad = lane >> 4, l16 = lane & 15;
    int r0 = blockIdx.x * 32;
    int cs = w * 32;

    // ---- stage bias (128 f32) ----
    if (tid < 32) *(float4*)(bias_s + tid * 4) = *(const float4*)(bias + tid * 4);

    // ---- stage x tile: thread covers row (tid>>3), cols [(tid&7)*16, +16) ----
    {
        int row = tid >> 3;
        int c0 = (tid & 7) * 16;
        int grow = r0 + row;
        u32x4 o0 = {0, 0, 0, 0}, o1 = {0, 0, 0, 0};
        if (grow < N) {
            const float4* xp = (const float4*)(x + ((size_t)grow << 7) + c0);
            float4 f0 = xp[0], f1 = xp[1], f2 = xp[2], f3 = xp[3];
            o0[0] = (unsigned)f2bf(f0.x) | ((unsigned)f2bf(f0.y) << 16);
            o0[1] = (unsigned)f2bf(f0.z) | ((unsigned)f2bf(f0.w) << 16);
            o0[2] = (unsigned)f2bf(f1.x) | ((unsigned)f2bf(f1.y) << 16);
            o0[3] = (unsigned)f2bf(f1.z) | ((unsigned)f2bf(f1.w) << 16);
            o1[0] = (unsigned)f2bf(f2.x) | ((unsigned)f2bf(f2.y) << 16);
            o1[1] = (unsigned)f2bf(f2.z) | ((unsigned)f2bf(f2.w) << 16);
            o1[2] = (unsigned)f2bf(f3.x) | ((unsigned)f2bf(f3.y) << 16);
            o1[3] = (unsigned)f2bf(f3.z) | ((unsigned)f2bf(f3.w) << 16);
        }
        *(u32x4*)(&X[row][c0])     = o0;
        *(u32x4*)(&X[row][c0 + 8]) = o1;
    }
    __syncthreads();

    // ---- GEMM: wave computes 32 rows x 32 cols, B-frags shared ----
    f32x4 ac[2][2];
    ac[0][0] = (f32x4){0.f, 0.f, 0.f, 0.f}; ac[0][1] = (f32x4){0.f, 0.f, 0.f, 0.f};
    ac[1][0] = (f32x4){0.f, 0.f, 0.f, 0.f}; ac[1][1] = (f32x4){0.f, 0.f, 0.f, 0.f};
#pragma unroll
    for (int k0 = 0; k0 < 128; k0 += 32) {
        s16x8 b0 = *(const s16x8*)(Wt + ((size_t)(cs + l16) << 7) + quad * 8 + k0);
        s16x8 b1 = *(const s16x8*)(Wt + ((size_t)(cs + 16 + l16) << 7) + quad * 8 + k0);
        s16x8 a0 = *(const s16x8*)(&X[l16][quad * 8 + k0]);
        s16x8 a1 = *(const s16x8*)(&X[16 + l16][quad * 8 + k0]);
        ac[0][0] = __builtin_amdgcn_mfma_f32_16x16x32_bf16(a0, b0, ac[0][0], 0, 0, 0);
        ac[0][1] = __builtin_amdgcn_mfma_f32_16x16x32_bf16(a0, b1, ac[0][1], 0, 0, 0);
        ac[1][0] = __builtin_amdgcn_mfma_f32_16x16x32_bf16(a1, b0, ac[1][0], 0, 0, 0);
        ac[1][1] = __builtin_amdgcn_mfma_f32_16x16x32_bf16(a1, b1, ac[1][1], 0, 0, 0);
    }

    // ---- dump acc+bias to LDS Z (fragment scatter stays in LDS) ----
#pragma unroll
    for (int rt = 0; rt < 2; ++rt) {
#pragma unroll
        for (int c = 0; c < 2; ++c) {
            int col = cs + c * 16 + l16;
            float bv = bias_s[col];
#pragma unroll
            for (int reg = 0; reg < 4; ++reg) {
                Z[rt * 16 + quad * 4 + reg][col] = ac[rt][c][reg] + bv;
            }
        }
    }
    __syncthreads();

    // ---- pass 2: row-contiguous vector stores ----
    {
        int row = tid >> 3;
        int c0 = (tid & 7) * 16;
        int grow = r0 + row;
        if (grow < N) {
            u32x4 ob0, ob1, o8;
#pragma unroll
            for (int j = 0; j < 4; ++j) {
                float v0 = Z[row][c0 + 2 * j];
                float v1 = Z[row][c0 + 2 * j + 1];
                float v2 = Z[row][c0 + 8 + 2 * j];
                float v3 = Z[row][c0 + 8 + 2 * j + 1];
                ob0[j] = (unsigned)f2bf(v0) | ((unsigned)f2bf(v1) << 16);
                ob1[j] = (unsigned)f2bf(v2) | ((unsigned)f2bf(v3) << 16);
                float w0 = Z[row][c0 + 4 * j], w1 = Z[row][c0 + 4 * j + 1];
                float w2 = Z[row][c0 + 4 * j + 2], w3 = Z[row][c0 + 4 * j + 3];
                o8[j] = (unsigned)f2fp8(w0) | ((unsigned)f2fp8(w1) << 8)
                      | ((unsigned)f2fp8(w2) << 16) | ((unsigned)f2fp8(w3) << 24);
            }
            *(u32x4*)(hb + ((size_t)grow << 7) + c0)     = ob0;
            *(u32x4*)(hb + ((size_t)grow << 7) + c0 + 8) = ob1;
            *(u32x4*)(h8 + ((size_t)grow << 7) + c0)     = o8;
        }
    }
}

// ---------------- aggregation-only kernel (round-4 form, ushort srcidx) ----------------

__global__ __launch_bounds__(256) void aggregate(const unsigned char* __restrict__ h8in,
                                                 const int* __restrict__ rowptr,
                                                 const unsigned short* __restrict__ srcidx,
                                                 const float* __restrict__ dinv,
                                                 unsigned short* __restrict__ mout, int N) {
    int tid = threadIdx.x;
    int w = tid >> 6, lane = tid & 63;
    int g = lane >> 3, li = lane & 7;
    int nd = blockIdx.x * 32 + w * 8 + g;
    bool nv = nd < N;

    int e  = nv ? rowptr[nd] : 0;
    int ee = nv ? rowptr[nd + 1] : 0;
    float di = nv ? dinv[nd] : 0.f;

    const unsigned char* hsl = h8in + li * 16;   // lane's 16-B slice of a row

    float a[16];
#pragma unroll
    for (int j = 0; j < 16; ++j) a[j] = 0.f;

#define GIDX(jj) (((jj) < ee) ? (int)srcidx[(jj)] : -1)
    int jA = e;
    int iA0 = GIDX(jA + 0), iA1 = GIDX(jA + 1), iA2 = GIDX(jA + 2), iA3 = GIDX(jA + 3);
    u32x4 A0 = {0, 0, 0, 0}, A1 = {0, 0, 0, 0}, A2 = {0, 0, 0, 0}, A3 = {0, 0, 0, 0};
    if (iA0 >= 0) A0 = *(const u32x4*)(hsl + ((size_t)iA0 << 7));
    if (iA1 >= 0) A1 = *(const u32x4*)(hsl + ((size_t)iA1 << 7));
    if (iA2 >= 0) A2 = *(const u32x4*)(hsl + ((size_t)iA2 << 7));
    if (iA3 >= 0) A3 = *(const u32x4*)(hsl + ((size_t)iA3 << 7));
    int jB = jA + 4;
    int iB0 = GIDX(jB + 0), iB1 = GIDX(jB + 1), iB2 = GIDX(jB + 2), iB3 = GIDX(jB + 3);

    while (__any(jA < ee)) {
        u32x4 B0 = {0, 0, 0, 0}, B1v = {0, 0, 0, 0}, B2v = {0, 0, 0, 0}, B3 = {0, 0, 0, 0};
        if (iB0 >= 0) B0  = *(const u32x4*)(hsl + ((size_t)iB0 << 7));
        if (iB1 >= 0) B1v = *(const u32x4*)(hsl + ((size_t)iB1 << 7));
        if (iB2 >= 0) B2v = *(const u32x4*)(hsl + ((size_t)iB2 << 7));
        if (iB3 >= 0) B3  = *(const u32x4*)(hsl + ((size_t)iB3 << 7));
        int jC = jB + 4;
        int iC0 = GIDX(jC + 0), iC1 = GIDX(jC + 1), iC2 = GIDX(jC + 2), iC3 = GIDX(jC + 3);
        acc_fp8x16(a, A0);
        acc_fp8x16(a, A1);
        acc_fp8x16(a, A2);
        acc_fp8x16(a, A3);
        jA = jB; A0 = B0; A1 = B1v; A2 = B2v; A3 = B3;
        jB = jC; iB0 = iC0; iB1 = iC1; iB2 = iC2; iB3 = iC3;
    }
#undef GIDX

    if (nv) {
        u32x4 o0, o1;
#pragma unroll
        for (int j = 0; j < 4; ++j) {
            unsigned lo0 = f2bf(a[2 * j]     * di);
            unsigned hi0 = f2bf(a[2 * j + 1] * di);
            o0[j] = lo0 | (hi0 << 16);
            unsigned lo1 = f2bf(a[8 + 2 * j]     * di);
            unsigned hi1 = f2bf(a[8 + 2 * j + 1] * di);
            o1[j] = lo1 | (hi1 << 16);
        }
        unsigned short* mp = mout + ((size_t)nd << 7) + li * 16;
        *(u32x4*)(mp)     = o0;
        *(u32x4*)(mp + 8) = o1;
    }
}

// ---------------- MLP + LN kernel (round-8 form, known-good) ----------------

__global__ __launch_bounds__(256) void mlp_ln(const unsigned short* __restrict__ hin,
                                              const unsigned short* __restrict__ m,
                                              const unsigned short* __restrict__ W1t,
                                              const float* __restrict__ B1,
                                              const unsigned short* __restrict__ W2t,
                                              const float* __restrict__ B2,
                                              const float* __restrict__ G,
                                              const float* __restrict__ Bb,
                                              unsigned short* __restrict__ hout,
                                              unsigned char* __restrict__ h8out,
                                              float* __restrict__ out_f32, int N) {
    __shared__ unsigned short M[32][132];   // +4 pad: conflict-light b128 A-frag reads
    __shared__ unsigned short P[32][132];
    __shared__ float s1p[4][32], s2p[4][32];

    int tid = threadIdx.x;
    int w = tid >> 6, lane = tid & 63;
    int quad = lane >> 4, l16 = lane & 15;
    int r0 = blockIdx.x * 32;
    int cs = w * 32;

    // ---- load m tile: 512 chunks of 16 B (8 bf16) ----
#pragma unroll
    for (int cc = 0; cc < 2; ++cc) {
        int c = tid + cc * 256;
        int row = c >> 4, colc = (c & 15) * 8;
        int grow = r0 + row;
        u32x4 v = {0, 0, 0, 0};
        if (grow < N) v = *(const u32x4*)(m + ((size_t)grow << 7) + colc);
        *(u32x4*)(&M[row][colc]) = v;
    }
    __syncthreads();

    // ---- prefetch residual (used after GEMM2; covered by both GEMMs) ----
    unsigned short hvr[2][2][4];
#pragma unroll
    for (int rt = 0; rt < 2; ++rt) {
#pragma unroll
        for (int c = 0; c < 2; ++c) {
            int col = cs + c * 16 + l16;
#pragma unroll
            for (int reg = 0; reg < 4; ++reg) {
                int grow = r0 + rt * 16 + quad * 4 + reg;
                hvr[rt][c][reg] = (grow < N) ? hin[((size_t)grow << 7) + col] : (unsigned short)0;
            }
        }
    }

    // ---- GEMM1: relu(m @ W1 + b1); wave: 32 rows x 32 cols, B-frags shared ----
    f32x4 ac1[2][2];
    ac1[0][0] = (f32x4){0.f, 0.f, 0.f, 0.f}; ac1[0][1] = (f32x4){0.f, 0.f, 0.f, 0.f};
    ac1[1][0] = (f32x4){0.f, 0.f, 0.f, 0.f}; ac1[1][1] = (f32x4){0.f, 0.f, 0.f, 0.f};
#pragma unroll
    for (int k0 = 0; k0 < 128; k0 += 32) {
        s16x8 b0 = *(const s16x8*)(W1t + ((size_t)(cs + l16) << 7) + quad * 8 + k0);
        s16x8 b1 = *(const s16x8*)(W1t + ((size_t)(cs + 16 + l16) << 7) + quad * 8 + k0);
        s16x8 a0 = *(const s16x8*)(&M[l16][quad * 8 + k0]);
        s16x8 a1 = *(const s16x8*)(&M[16 + l16][quad * 8 + k0]);
        ac1[0][0] = __builtin_amdgcn_mfma_f32_16x16x32_bf16(a0, b0, ac1[0][0], 0, 0, 0);
        ac1[0][1] = __builtin_amdgcn_mfma_f32_16x16x32_bf16(a0, b1, ac1[0][1], 0, 0, 0);
        ac1[1][0] = __builtin_amdgcn_mfma_f32_16x16x32_bf16(a1, b0, ac1[1][0], 0, 0, 0);
        ac1[1][1] = __builtin_amdgcn_mfma_f32_16x16x32_bf16(a1, b1, ac1[1][1], 0, 0, 0);
    }
#pragma unroll
    for (int rt = 0; rt < 2; ++rt) {
#pragma unroll
        for (int c = 0; c < 2; ++c) {
            int col = cs + c * 16 + l16;
            float bv = B1[col];
#pragma unroll
            for (int reg = 0; reg < 4; ++reg) {
                float v = fmaxf(ac1[rt][c][reg] + bv, 0.f);
                P[rt * 16 + quad * 4 + reg][col] = f2bf(v);
            }
        }
    }
    __syncthreads();

    // ---- GEMM2: P @ W2 ----
    f32x4 ac2[2][2];
    ac2[0][0] = (f32x4){0.f, 0.f, 0.f, 0.f}; ac2[0][1] = (f32x4){0.f, 0.f, 0.f, 0.f};
    ac2[1][0] = (f32x4){0.f, 0.f, 0.f, 0.f}; ac2[1][1] = (f32x4){0.f, 0.f, 0.f, 0.f};
#pragma unroll
    for (int k0 = 0; k0 < 128; k0 += 32) {
        s16x8 b0 = *(const s16x8*)(W2t + ((size_t)(cs + l16) << 7) + quad * 8 + k0);
        s16x8 b1 = *(const s16x8*)(W2t + ((size_t)(cs + 16 + l16) << 7) + quad * 8 + k0);
        s16x8 a0 = *(const s16x8*)(&P[l16][quad * 8 + k0]);
        s16x8 a1 = *(const s16x8*)(&P[16 + l16][quad * 8 + k0]);
        ac2[0][0] = __builtin_amdgcn_mfma_f32_16x16x32_bf16(a0, b0, ac2[0][0], 0, 0, 0);
        ac2[0][1] = __builtin_amdgcn_mfma_f32_16x16x32_bf16(a0, b1, ac2[0][1], 0, 0, 0);
        ac2[1][0] = __builtin_amdgcn_mfma_f32_16x16x32_bf16(a1, b0, ac2[1][0], 0, 0, 0);
        ac2[1][1] = __builtin_amdgcn_mfma_f32_16x16x32_bf16(a1, b1, ac2[1][1], 0, 0, 0);
    }

    // ---- epilogue: residual + LN (cross-wave row sums via LDS partials) ----
    float z[2][2][4];
    float ps1[2][4] = {{0, 0, 0, 0}, {0, 0, 0, 0}};
    float ps2[2][4] = {{0, 0, 0, 0}, {0, 0, 0, 0}};
#pragma unroll
    for (int rt = 0; rt < 2; ++rt) {
#pragma unroll
        for (int c = 0; c < 2; ++c) {
            int col = cs + c * 16 + l16;
            float b2v = B2[col];
#pragma unroll
            for (int reg = 0; reg < 4; ++reg) {
                float hv = bf2f(hvr[rt][c][reg]);
                float zz = ac2[rt][c][reg] + b2v + hv;
                z[rt][c][reg] = zz;
                ps1[rt][reg] += zz;
                ps2[rt][reg] += zz * zz;
            }
        }
    }
#pragma unroll
    for (int off = 1; off < 16; off <<= 1) {
#pragma unroll
        for (int rt = 0; rt < 2; ++rt) {
#pragma unroll
            for (int reg = 0; reg < 4; ++reg) {
                ps1[rt][reg] += __shfl_xor(ps1[rt][reg], off, 64);
                ps2[rt][reg] += __shfl_xor(ps2[rt][reg], off, 64);
            }
        }
    }
    if (l16 == 0) {
#pragma unroll
        for (int rt = 0; rt < 2; ++rt) {
#pragma unroll
            for (int reg = 0; reg < 4; ++reg) {
                s1p[w][rt * 16 + quad * 4 + reg] = ps1[rt][reg];
                s2p[w][rt * 16 + quad * 4 + reg] = ps2[rt][reg];
            }
        }
    }
    __syncthreads();

#pragma unroll
    for (int rt = 0; rt < 2; ++rt) {
#pragma unroll
        for (int reg = 0; reg < 4; ++reg) {
            int row = rt * 16 + quad * 4 + reg;
            float S1 = s1p[0][row] + s1p[1][row] + s1p[2][row] + s1p[3][row];
            float S2 = s2p[0][row] + s2p[1][row] + s2p[2][row] + s2p[3][row];
            float mean = S1 * (1.0f / 128.0f);
            float var = S2 * (1.0f / 128.0f) - mean * mean;
            float rs = rsqrtf(var + LN_EPS);
            int grow = r0 + row;
            if (grow < N) {
#pragma unroll
                for (int c = 0; c < 2; ++c) {
                    int col = cs + c * 16 + l16;
                    float o = (z[rt][c][reg] - mean) * rs * G[col] + Bb[col];
                    if (out_f32) {
                        out_f32[((size_t)grow << 7) + col] = o;   // last layer: f32 only
                    } else {
                        hout[((size_t)grow << 7) + col] = f2bf(o);
                        h8out[((size_t)grow << 7) + col] = f2fp8(o);
                    }
                }
            }
        }
    }
}

// ---------------- launch ----------------

extern "C" void kernel_launch(void* const* d_in, const int* in_sizes, int n_in,
                              void* d_out, int out_size, void* d_ws, size_t ws_size,
                              hipStream_t stream) {
    const float* x    = (const float*)d_in[0];
    const int*   ei   = (const int*)d_in[1];
    const float* in_w = (const float*)d_in[2];
    const float* in_b = (const float*)d_in[3];
    const float* w1   = (const float*)d_in[4];
    const float* b1   = (const float*)d_in[5];
    const float* w2   = (const float*)d_in[6];
    const float* b2   = (const float*)d_in[7];
    const float* ln_g = (const float*)d_in[8];
    const float* ln_b = (const float*)d_in[9];

    const int N = in_sizes[0] / DIM;               // 50000
    const int E = in_sizes[1] / 2;                 // 640000
    const int LAYERS = in_sizes[4] / (DIM * DIM);  // 3

    const int* e_src = ei;
    const int* e_dst = ei + E;

    // workspace layout
    char* ws = (char*)d_ws;
    unsigned short* hb0    = (unsigned short*)ws;  ws += (size_t)N * DIM * 2;
    unsigned short* hb1    = (unsigned short*)ws;  ws += (size_t)N * DIM * 2;
    unsigned char*  h8a    = (unsigned char*)ws;   ws += (size_t)N * DIM;
    unsigned char*  h8b    = (unsigned char*)ws;   ws += (size_t)N * DIM;
    int*            counts = (int*)ws;             ws += (size_t)N * 4;
    int*            rowptr = (int*)ws;             ws += (size_t)(N + 1) * 4;
    int*            cursor = (int*)ws;             ws += (size_t)N * 4;
    float*          dinv   = (float*)ws;           ws += (size_t)N * 4;
    unsigned short* srcidx = (unsigned short*)ws;  ws += (size_t)E * 2;
    unsigned short* wt     = (unsigned short*)ws;  ws += (size_t)(2 * LAYERS + 1) * DIM * DIM * 2;
    unsigned short* mbuf   = (unsigned short*)ws;  ws += (size_t)N * DIM * 2;

    const int nScanBlocks = (N + 1023) / 1024;
    const int nMat = 2 * LAYERS + 1;
    const int nWblk = nMat * 8;

    // --- CSR build + weight cvt + input projection ---
    (void)hipMemsetAsync(counts, 0, (size_t)N * 4, stream);
    prep<<<nWblk + (E + 1023) / 1024, 256, 0, stream>>>(in_w, w1, w2, wt, LAYERS,
                                                        e_dst, E, counts, nWblk);
    scan_all<<<nScanBlocks, 256, 0, stream>>>(counts, N, rowptr, cursor, dinv, E);
    gemm_bias32<<<(N + 31) / 32, 256, 0, stream>>>(x, wt, in_b, hb0, h8a, N);
    fill_csr<<<(E + 1023) / 1024, 256, 0, stream>>>(e_src, e_dst, E, cursor, srcidx);

    const unsigned short* w1t = wt + (size_t)DIM * DIM;
    const unsigned short* w2t = wt + (size_t)(1 + LAYERS) * DIM * DIM;

    // --- layers (ping-pong; gather reads pre-update fp8 table) ---
    int tile_grid = (N + 31) / 32;
    unsigned short* hin  = hb0;  unsigned char* h8in  = h8a;
    unsigned short* hout = hb1;  unsigned char* h8out = h8b;
    for (int i = 0; i < LAYERS; ++i) {
        float* out = (i == LAYERS - 1) ? (float*)d_out : nullptr;
        aggregate<<<tile_grid, 256, 0, stream>>>(h8in, rowptr, srcidx, dinv, mbuf, N);
        mlp_ln<<<tile_grid, 256, 0, stream>>>(hin, mbuf,
                                              w1t + (size_t)i * DIM * DIM, b1 + (size_t)i * DIM,
                                              w2t + (size_t)i * DIM * DIM, b2 + (size_t)i * DIM,
                                              ln_g + (size_t)i * DIM, ln_b + (size_t)i * DIM,
                                              hout, h8out, out, N);
        unsigned short* t = hin; hin = hout; hout = t;
        unsigned char* t8 = h8in; h8in = h8out; h8out = t8;
    }
}

// Round 11
// 315.446 us; speedup vs baseline: 4.7530x; 1.0196x over previous
//
#include <hip/hip_runtime.h>
#include <hip/hip_fp8.h>

#define DIM 128
#define LN_EPS 1e-5f

typedef __attribute__((ext_vector_type(8))) short s16x8;   // 8 bf16 in 4 VGPRs
typedef __attribute__((ext_vector_type(4))) float f32x4;
typedef __attribute__((ext_vector_type(2))) float f32x2;
typedef __attribute__((ext_vector_type(4))) unsigned int u32x4;

__device__ __forceinline__ unsigned short f2bf(float f) {
    unsigned u = __float_as_uint(f);
    unsigned r = u + 0x7fffu + ((u >> 16) & 1u);   // round-to-nearest-even
    return (unsigned short)(r >> 16);
}
__device__ __forceinline__ float bf2f(unsigned short b) {
    return __uint_as_float(((unsigned)b) << 16);
}
__device__ __forceinline__ unsigned char f2fp8(float f) {
    return (unsigned char)__hip_cvt_float_to_fp8(f, __HIP_SATFINITE, __HIP_E4M3);
}
// accumulate 4 fp8 bytes (linear col order) into a[0..3]
__device__ __forceinline__ void acc_fp8x4(float* a, unsigned v) {
    f32x2 lo = __builtin_amdgcn_cvt_pk_f32_fp8(v, false);  // bytes 0,1
    f32x2 hi = __builtin_amdgcn_cvt_pk_f32_fp8(v, true);   // bytes 2,3
    a[0] += lo[0]; a[1] += lo[1]; a[2] += hi[0]; a[3] += hi[1];
}
// accumulate a full u32x4 (16 fp8 bytes) into a[0..15]
__device__ __forceinline__ void acc_fp8x16(float* a, u32x4 v) {
    acc_fp8x4(a + 0,  v[0]);
    acc_fp8x4(a + 4,  v[1]);
    acc_fp8x4(a + 8,  v[2]);
    acc_fp8x4(a + 12, v[3]);
}

// ---------------- prep: weight cvt (f32 -> bf16 transposed) + degree count ----------------

__global__ __launch_bounds__(256) void prep(const float* __restrict__ in_w,
                                            const float* __restrict__ w1,
                                            const float* __restrict__ w2,
                                            unsigned short* __restrict__ wt, int L,
                                            const int* __restrict__ dst, int E,
                                            int* __restrict__ counts, int nWblk) {
    if ((int)blockIdx.x < nWblk) {
        int mat = blockIdx.x >> 3, part = blockIdx.x & 7;
        const float* src;
        if (mat == 0) src = in_w;
        else if (mat <= L) src = w1 + (size_t)(mat - 1) * DIM * DIM;
        else src = w2 + (size_t)(mat - 1 - L) * DIM * DIM;
        unsigned short* dstw = wt + (size_t)mat * DIM * DIM;
        int base = part * 2048 + threadIdx.x;
#pragma unroll
        for (int j = 0; j < 8; ++j) {
            int i = base + j * 256;
            int k = i >> 7, n = i & 127;
            dstw[n * DIM + k] = f2bf(src[i]);
        }
    } else {
        int b = blockIdx.x - nWblk;
        int i = (b * 256 + threadIdx.x) * 4;
        if (i + 3 < E) {
            int4 d = *(const int4*)(dst + i);
            atomicAdd(&counts[d.x], 1);
            atomicAdd(&counts[d.y], 1);
            atomicAdd(&counts[d.z], 1);
            atomicAdd(&counts[d.w], 1);
        } else {
            for (int j = i; j < E; ++j) atomicAdd(&counts[dst[j]], 1);
        }
    }
}

// ---------------- scan (single dispatch): block offset computed in-block ----------------

__global__ __launch_bounds__(256) void scan_all(const int* __restrict__ counts, int n,
                                                int* __restrict__ rowptr,
                                                int* __restrict__ cursor,
                                                float* __restrict__ dinv, int E) {
    __shared__ int wsum[4];
    int tid = threadIdx.x;
    int lane = tid & 63, wid = tid >> 6;

    int limit = blockIdx.x * 1024;            // multiple of 1024
    int acc = 0;
    for (int i = tid * 4; i < limit; i += 1024) {
        int4 c4 = *(const int4*)(counts + i);
        acc += c4.x + c4.y + c4.z + c4.w;
    }
#pragma unroll
    for (int off = 32; off > 0; off >>= 1) acc += __shfl_xor(acc, off, 64);
    if (lane == 0) wsum[wid] = acc;
    __syncthreads();
    int bofs = wsum[0] + wsum[1] + wsum[2] + wsum[3];
    __syncthreads();                          // wsum reused below

    if (blockIdx.x == 0 && tid == 0) rowptr[n] = E;

    int base = blockIdx.x * 1024 + tid * 4;
    int v[4];
#pragma unroll
    for (int j = 0; j < 4; ++j) {
        int i = base + j;
        v[j] = (i < n) ? counts[i] : 0;
    }
    int tsum = v[0] + v[1] + v[2] + v[3];
    int incl = tsum;
#pragma unroll
    for (int off = 1; off < 64; off <<= 1) {
        int t = __shfl_up(incl, off, 64);
        if (lane >= off) incl += t;
    }
    if (lane == 63) wsum[wid] = incl;
    __syncthreads();
    int wofs = 0;
    for (int w = 0; w < 4; ++w)
        if (w < wid) wofs += wsum[w];
    int excl = bofs + wofs + (incl - tsum);
#pragma unroll
    for (int j = 0; j < 4; ++j) {
        int i = base + j;
        if (i < n) {
            rowptr[i] = excl;
            cursor[i] = excl;
            dinv[i] = 1.0f / (float)((v[j] > 1) ? v[j] : 1);
            excl += v[j];
        }
    }
}

// ---------------- CSR fill ----------------

__global__ void fill_csr(const int* __restrict__ src, const int* __restrict__ dst, int E,
                         int* __restrict__ cursor, unsigned short* __restrict__ srcidx) {
    int i = (blockIdx.x * 256 + threadIdx.x) * 4;
    if (i + 3 < E) {
        int4 s4 = *(const int4*)(src + i);
        int4 d4 = *(const int4*)(dst + i);
        int p0 = atomicAdd(&cursor[d4.x], 1); srcidx[p0] = (unsigned short)s4.x;
        int p1 = atomicAdd(&cursor[d4.y], 1); srcidx[p1] = (unsigned short)s4.y;
        int p2 = atomicAdd(&cursor[d4.z], 1); srcidx[p2] = (unsigned short)s4.z;
        int p3 = atomicAdd(&cursor[d4.w], 1); srcidx[p3] = (unsigned short)s4.w;
    } else {
        for (int j = i; j < E; ++j) {
            int p = atomicAdd(&cursor[dst[j]], 1);
            srcidx[p] = (unsigned short)src[j];
        }
    }
}

// ---------------- input projection: 32 rows/block, LDS-transposed epilogue ----------
// (round-10 form, verified bit-exact)

__global__ __launch_bounds__(256) void gemm_bias32(const float* __restrict__ x,
                                                   const unsigned short* __restrict__ Wt,
                                                   const float* __restrict__ bias,
                                                   unsigned short* __restrict__ hb,
                                                   unsigned char* __restrict__ h8, int N) {
    __shared__ __align__(16) unsigned short X[32][136];
    __shared__ __align__(16) float Z[32][132];
    __shared__ __align__(16) float bias_s[128];

    int tid = threadIdx.x;
    int w = tid >> 6, lane = tid & 63;
    int quad = lane >> 4, l16 = lane & 15;
    int r0 = blockIdx.x * 32;
    int cs = w * 32;

    // ---- stage bias (128 f32) ----
    if (tid < 32) *(float4*)(bias_s + tid * 4) = *(const float4*)(bias + tid * 4);

    // ---- stage x tile: thread covers row (tid>>3), cols [(tid&7)*16, +16) ----
    {
        int row = tid >> 3;
        int c0 = (tid & 7) * 16;
        int grow = r0 + row;
        u32x4 o0 = {0, 0, 0, 0}, o1 = {0, 0, 0, 0};
        if (grow < N) {
            const float4* xp = (const float4*)(x + ((size_t)grow << 7) + c0);
            float4 f0 = xp[0], f1 = xp[1], f2 = xp[2], f3 = xp[3];
            o0[0] = (unsigned)f2bf(f0.x) | ((unsigned)f2bf(f0.y) << 16);
            o0[1] = (unsigned)f2bf(f0.z) | ((unsigned)f2bf(f0.w) << 16);
            o0[2] = (unsigned)f2bf(f1.x) | ((unsigned)f2bf(f1.y) << 16);
            o0[3] = (unsigned)f2bf(f1.z) | ((unsigned)f2bf(f1.w) << 16);
            o1[0] = (unsigned)f2bf(f2.x) | ((unsigned)f2bf(f2.y) << 16);
            o1[1] = (unsigned)f2bf(f2.z) | ((unsigned)f2bf(f2.w) << 16);
            o1[2] = (unsigned)f2bf(f3.x) | ((unsigned)f2bf(f3.y) << 16);
            o1[3] = (unsigned)f2bf(f3.z) | ((unsigned)f2bf(f3.w) << 16);
        }
        *(u32x4*)(&X[row][c0])     = o0;
        *(u32x4*)(&X[row][c0 + 8]) = o1;
    }
    __syncthreads();

    // ---- GEMM: wave computes 32 rows x 32 cols, B-frags shared ----
    f32x4 ac[2][2];
    ac[0][0] = (f32x4){0.f, 0.f, 0.f, 0.f}; ac[0][1] = (f32x4){0.f, 0.f, 0.f, 0.f};
    ac[1][0] = (f32x4){0.f, 0.f, 0.f, 0.f}; ac[1][1] = (f32x4){0.f, 0.f, 0.f, 0.f};
#pragma unroll
    for (int k0 = 0; k0 < 128; k0 += 32) {
        s16x8 b0 = *(const s16x8*)(Wt + ((size_t)(cs + l16) << 7) + quad * 8 + k0);
        s16x8 b1 = *(const s16x8*)(Wt + ((size_t)(cs + 16 + l16) << 7) + quad * 8 + k0);
        s16x8 a0 = *(const s16x8*)(&X[l16][quad * 8 + k0]);
        s16x8 a1 = *(const s16x8*)(&X[16 + l16][quad * 8 + k0]);
        ac[0][0] = __builtin_amdgcn_mfma_f32_16x16x32_bf16(a0, b0, ac[0][0], 0, 0, 0);
        ac[0][1] = __builtin_amdgcn_mfma_f32_16x16x32_bf16(a0, b1, ac[0][1], 0, 0, 0);
        ac[1][0] = __builtin_amdgcn_mfma_f32_16x16x32_bf16(a1, b0, ac[1][0], 0, 0, 0);
        ac[1][1] = __builtin_amdgcn_mfma_f32_16x16x32_bf16(a1, b1, ac[1][1], 0, 0, 0);
    }

    // ---- dump acc+bias to LDS Z (fragment scatter stays in LDS) ----
#pragma unroll
    for (int rt = 0; rt < 2; ++rt) {
#pragma unroll
        for (int c = 0; c < 2; ++c) {
            int col = cs + c * 16 + l16;
            float bv = bias_s[col];
#pragma unroll
            for (int reg = 0; reg < 4; ++reg) {
                Z[rt * 16 + quad * 4 + reg][col] = ac[rt][c][reg] + bv;
            }
        }
    }
    __syncthreads();

    // ---- pass 2: row-contiguous vector stores ----
    {
        int row = tid >> 3;
        int c0 = (tid & 7) * 16;
        int grow = r0 + row;
        if (grow < N) {
            u32x4 ob0, ob1, o8;
#pragma unroll
            for (int j = 0; j < 4; ++j) {
                float v0 = Z[row][c0 + 2 * j];
                float v1 = Z[row][c0 + 2 * j + 1];
                float v2 = Z[row][c0 + 8 + 2 * j];
                float v3 = Z[row][c0 + 8 + 2 * j + 1];
                ob0[j] = (unsigned)f2bf(v0) | ((unsigned)f2bf(v1) << 16);
                ob1[j] = (unsigned)f2bf(v2) | ((unsigned)f2bf(v3) << 16);
                float w0 = Z[row][c0 + 4 * j], w1 = Z[row][c0 + 4 * j + 1];
                float w2 = Z[row][c0 + 4 * j + 2], w3 = Z[row][c0 + 4 * j + 3];
                o8[j] = (unsigned)f2fp8(w0) | ((unsigned)f2fp8(w1) << 8)
                      | ((unsigned)f2fp8(w2) << 16) | ((unsigned)f2fp8(w3) << 24);
            }
            *(u32x4*)(hb + ((size_t)grow << 7) + c0)     = ob0;
            *(u32x4*)(hb + ((size_t)grow << 7) + c0 + 8) = ob1;
            *(u32x4*)(h8 + ((size_t)grow << 7) + c0)     = o8;
        }
    }
}

// ---------------- aggregation-only kernel (round-4 form, ushort srcidx) ----------------

__global__ __launch_bounds__(256) void aggregate(const unsigned char* __restrict__ h8in,
                                                 const int* __restrict__ rowptr,
                                                 const unsigned short* __restrict__ srcidx,
                                                 const float* __restrict__ dinv,
                                                 unsigned short* __restrict__ mout, int N) {
    int tid = threadIdx.x;
    int w = tid >> 6, lane = tid & 63;
    int g = lane >> 3, li = lane & 7;
    int nd = blockIdx.x * 32 + w * 8 + g;
    bool nv = nd < N;

    int e  = nv ? rowptr[nd] : 0;
    int ee = nv ? rowptr[nd + 1] : 0;
    float di = nv ? dinv[nd] : 0.f;

    const unsigned char* hsl = h8in + li * 16;   // lane's 16-B slice of a row

    float a[16];
#pragma unroll
    for (int j = 0; j < 16; ++j) a[j] = 0.f;

#define GIDX(jj) (((jj) < ee) ? (int)srcidx[(jj)] : -1)
    int jA = e;
    int iA0 = GIDX(jA + 0), iA1 = GIDX(jA + 1), iA2 = GIDX(jA + 2), iA3 = GIDX(jA + 3);
    u32x4 A0 = {0, 0, 0, 0}, A1 = {0, 0, 0, 0}, A2 = {0, 0, 0, 0}, A3 = {0, 0, 0, 0};
    if (iA0 >= 0) A0 = *(const u32x4*)(hsl + ((size_t)iA0 << 7));
    if (iA1 >= 0) A1 = *(const u32x4*)(hsl + ((size_t)iA1 << 7));
    if (iA2 >= 0) A2 = *(const u32x4*)(hsl + ((size_t)iA2 << 7));
    if (iA3 >= 0) A3 = *(const u32x4*)(hsl + ((size_t)iA3 << 7));
    int jB = jA + 4;
    int iB0 = GIDX(jB + 0), iB1 = GIDX(jB + 1), iB2 = GIDX(jB + 2), iB3 = GIDX(jB + 3);

    while (__any(jA < ee)) {
        u32x4 B0 = {0, 0, 0, 0}, B1v = {0, 0, 0, 0}, B2v = {0, 0, 0, 0}, B3 = {0, 0, 0, 0};
        if (iB0 >= 0) B0  = *(const u32x4*)(hsl + ((size_t)iB0 << 7));
        if (iB1 >= 0) B1v = *(const u32x4*)(hsl + ((size_t)iB1 << 7));
        if (iB2 >= 0) B2v = *(const u32x4*)(hsl + ((size_t)iB2 << 7));
        if (iB3 >= 0) B3  = *(const u32x4*)(hsl + ((size_t)iB3 << 7));
        int jC = jB + 4;
        int iC0 = GIDX(jC + 0), iC1 = GIDX(jC + 1), iC2 = GIDX(jC + 2), iC3 = GIDX(jC + 3);
        acc_fp8x16(a, A0);
        acc_fp8x16(a, A1);
        acc_fp8x16(a, A2);
        acc_fp8x16(a, A3);
        jA = jB; A0 = B0; A1 = B1v; A2 = B2v; A3 = B3;
        jB = jC; iB0 = iC0; iB1 = iC1; iB2 = iC2; iB3 = iC3;
    }
#undef GIDX

    if (nv) {
        u32x4 o0, o1;
#pragma unroll
        for (int j = 0; j < 4; ++j) {
            unsigned lo0 = f2bf(a[2 * j]     * di);
            unsigned hi0 = f2bf(a[2 * j + 1] * di);
            o0[j] = lo0 | (hi0 << 16);
            unsigned lo1 = f2bf(a[8 + 2 * j]     * di);
            unsigned hi1 = f2bf(a[8 + 2 * j + 1] * di);
            o1[j] = lo1 | (hi1 << 16);
        }
        unsigned short* mp = mout + ((size_t)nd << 7) + li * 16;
        *(u32x4*)(mp)     = o0;
        *(u32x4*)(mp + 8) = o1;
    }
}

// ---------------- MLP + LN kernel: bit-exact LDS-routed epilogue ----------------
// ALL arithmetic identical to round-8 (same association in LN sums, same
// expression order for z and o). Only data routing changes:
//   residual: 16 scalar global loads -> 2 vector loads + LDS stage (R)
//   outputs:  32 scattered sub-word stores -> o routed through LDS Z (f32,
//             exact), then row-contiguous vector stores.
// Z (16896 B) aliases [M|P] — both dead after GEMM2; the s1p barrier orders it.

__global__ __launch_bounds__(256) void mlp_ln(const unsigned short* __restrict__ hin,
                                              const unsigned short* __restrict__ m,
                                              const unsigned short* __restrict__ W1t,
                                              const float* __restrict__ B1,
                                              const unsigned short* __restrict__ W2t,
                                              const float* __restrict__ B2,
                                              const float* __restrict__ G,
                                              const float* __restrict__ Bb,
                                              unsigned short* __restrict__ hout,
                                              unsigned char* __restrict__ h8out,
                                              float* __restrict__ out_f32, int N) {
    __shared__ __align__(16) char raw[26368];
    unsigned short (*M)[132] = (unsigned short (*)[132])raw;            // 0..8448
    unsigned short (*P)[132] = (unsigned short (*)[132])(raw + 8448);   // 8448..16896
    float (*Z)[132] = (float (*)[132])raw;                              // aliases M|P (after s1p sync)
    unsigned short (*R)[132] = (unsigned short (*)[132])(raw + 16896);  // 16896..25344
    float (*s1p)[32] = (float (*)[32])(raw + 25344);                    // 25344..25856
    float (*s2p)[32] = (float (*)[32])(raw + 25856);                    // 25856..26368

    int tid = threadIdx.x;
    int w = tid >> 6, lane = tid & 63;
    int quad = lane >> 4, l16 = lane & 15;
    int r0 = blockIdx.x * 32;
    int cs = w * 32;
    int prow = tid >> 3;            // pass-2 row (0..31)
    int pc0 = (tid & 7) * 16;       // pass-2 col base

    // ---- load m tile: 512 chunks of 16 B (8 bf16) ----
#pragma unroll
    for (int cc = 0; cc < 2; ++cc) {
        int c = tid + cc * 256;
        int row = c >> 4, colc = (c & 15) * 8;
        int grow = r0 + row;
        u32x4 v = {0, 0, 0, 0};
        if (grow < N) v = *(const u32x4*)(m + ((size_t)grow << 7) + colc);
        *(u32x4*)(&M[row][colc]) = v;
    }
    // ---- load residual tile row-contiguous -> R (same bits as scalar loads) ----
    {
        int grow = r0 + prow;
        u32x4 h0 = {0, 0, 0, 0}, h1 = {0, 0, 0, 0};
        if (grow < N) {
            h0 = *(const u32x4*)(hin + ((size_t)grow << 7) + pc0);
            h1 = *(const u32x4*)(hin + ((size_t)grow << 7) + pc0 + 8);
        }
        *(u32x4*)(&R[prow][pc0])     = h0;
        *(u32x4*)(&R[prow][pc0 + 8]) = h1;
    }
    __syncthreads();

    // ---- GEMM1: relu(m @ W1 + b1); wave: 32 rows x 32 cols, B-frags shared ----
    f32x4 ac1[2][2];
    ac1[0][0] = (f32x4){0.f, 0.f, 0.f, 0.f}; ac1[0][1] = (f32x4){0.f, 0.f, 0.f, 0.f};
    ac1[1][0] = (f32x4){0.f, 0.f, 0.f, 0.f}; ac1[1][1] = (f32x4){0.f, 0.f, 0.f, 0.f};
#pragma unroll
    for (int k0 = 0; k0 < 128; k0 += 32) {
        s16x8 b0 = *(const s16x8*)(W1t + ((size_t)(cs + l16) << 7) + quad * 8 + k0);
        s16x8 b1 = *(const s16x8*)(W1t + ((size_t)(cs + 16 + l16) << 7) + quad * 8 + k0);
        s16x8 a0 = *(const s16x8*)(&M[l16][quad * 8 + k0]);
        s16x8 a1 = *(const s16x8*)(&M[16 + l16][quad * 8 + k0]);
        ac1[0][0] = __builtin_amdgcn_mfma_f32_16x16x32_bf16(a0, b0, ac1[0][0], 0, 0, 0);
        ac1[0][1] = __builtin_amdgcn_mfma_f32_16x16x32_bf16(a0, b1, ac1[0][1], 0, 0, 0);
        ac1[1][0] = __builtin_amdgcn_mfma_f32_16x16x32_bf16(a1, b0, ac1[1][0], 0, 0, 0);
        ac1[1][1] = __builtin_amdgcn_mfma_f32_16x16x32_bf16(a1, b1, ac1[1][1], 0, 0, 0);
    }
#pragma unroll
    for (int rt = 0; rt < 2; ++rt) {
#pragma unroll
        for (int c = 0; c < 2; ++c) {
            int col = cs + c * 16 + l16;
            float bv = B1[col];
#pragma unroll
            for (int reg = 0; reg < 4; ++reg) {
                float v = fmaxf(ac1[rt][c][reg] + bv, 0.f);
                P[rt * 16 + quad * 4 + reg][col] = f2bf(v);
            }
        }
    }
    __syncthreads();

    // ---- GEMM2: P @ W2 ----
    f32x4 ac2[2][2];
    ac2[0][0] = (f32x4){0.f, 0.f, 0.f, 0.f}; ac2[0][1] = (f32x4){0.f, 0.f, 0.f, 0.f};
    ac2[1][0] = (f32x4){0.f, 0.f, 0.f, 0.f}; ac2[1][1] = (f32x4){0.f, 0.f, 0.f, 0.f};
#pragma unroll
    for (int k0 = 0; k0 < 128; k0 += 32) {
        s16x8 b0 = *(const s16x8*)(W2t + ((size_t)(cs + l16) << 7) + quad * 8 + k0);
        s16x8 b1 = *(const s16x8*)(W2t + ((size_t)(cs + 16 + l16) << 7) + quad * 8 + k0);
        s16x8 a0 = *(const s16x8*)(&P[l16][quad * 8 + k0]);
        s16x8 a1 = *(const s16x8*)(&P[16 + l16][quad * 8 + k0]);
        ac2[0][0] = __builtin_amdgcn_mfma_f32_16x16x32_bf16(a0, b0, ac2[0][0], 0, 0, 0);
        ac2[0][1] = __builtin_amdgcn_mfma_f32_16x16x32_bf16(a0, b1, ac2[0][1], 0, 0, 0);
        ac2[1][0] = __builtin_amdgcn_mfma_f32_16x16x32_bf16(a1, b0, ac2[1][0], 0, 0, 0);
        ac2[1][1] = __builtin_amdgcn_mfma_f32_16x16x32_bf16(a1, b1, ac2[1][1], 0, 0, 0);
    }

    // ---- epilogue: residual + LN — arithmetic IDENTICAL to round-8 ----
    float z[2][2][4];
    float ps1[2][4] = {{0, 0, 0, 0}, {0, 0, 0, 0}};
    float ps2[2][4] = {{0, 0, 0, 0}, {0, 0, 0, 0}};
#pragma unroll
    for (int rt = 0; rt < 2; ++rt) {
#pragma unroll
        for (int c = 0; c < 2; ++c) {
            int col = cs + c * 16 + l16;
            float b2v = B2[col];
#pragma unroll
            for (int reg = 0; reg < 4; ++reg) {
                float hv = bf2f(R[rt * 16 + quad * 4 + reg][col]);   // same bits as global read
                float zz = ac2[rt][c][reg] + b2v + hv;
                z[rt][c][reg] = zz;
                ps1[rt][reg] += zz;
                ps2[rt][reg] += zz * zz;
            }
        }
    }
#pragma unroll
    for (int off = 1; off < 16; off <<= 1) {
#pragma unroll
        for (int rt = 0; rt < 2; ++rt) {
#pragma unroll
            for (int reg = 0; reg < 4; ++reg) {
                ps1[rt][reg] += __shfl_xor(ps1[rt][reg], off, 64);
                ps2[rt][reg] += __shfl_xor(ps2[rt][reg], off, 64);
            }
        }
    }
    if (l16 == 0) {
#pragma unroll
        for (int rt = 0; rt < 2; ++rt) {
#pragma unroll
            for (int reg = 0; reg < 4; ++reg) {
                s1p[w][rt * 16 + quad * 4 + reg] = ps1[rt][reg];
                s2p[w][rt * 16 + quad * 4 + reg] = ps2[rt][reg];
            }
        }
    }
    __syncthreads();   // also: all waves past GEMM2 -> M|P dead -> Z writable

#pragma unroll
    for (int rt = 0; rt < 2; ++rt) {
#pragma unroll
        for (int reg = 0; reg < 4; ++reg) {
            int row = rt * 16 + quad * 4 + reg;
            float S1 = s1p[0][row] + s1p[1][row] + s1p[2][row] + s1p[3][row];
            float S2 = s2p[0][row] + s2p[1][row] + s2p[2][row] + s2p[3][row];
            float mean = S1 * (1.0f / 128.0f);
            float var = S2 * (1.0f / 128.0f) - mean * mean;
            float rs = rsqrtf(var + LN_EPS);
#pragma unroll
            for (int c = 0; c < 2; ++c) {
                int col = cs + c * 16 + l16;
                float o = (z[rt][c][reg] - mean) * rs * G[col] + Bb[col];  // same expr as r8
                Z[row][col] = o;   // exact f32 routed through LDS
            }
        }
    }
    __syncthreads();

    // ---- pass 2: row-contiguous vector stores (same rounding fns on same values) ----
    {
        int grow = r0 + prow;
        if (grow < N) {
            if (out_f32) {
                float* op = out_f32 + ((size_t)grow << 7) + pc0;
#pragma unroll
                for (int jj = 0; jj < 4; ++jj) {
                    f32x4 o4 = {Z[prow][pc0 + jj * 4], Z[prow][pc0 + jj * 4 + 1],
                                Z[prow][pc0 + jj * 4 + 2], Z[prow][pc0 + jj * 4 + 3]};
                    *(f32x4*)(op + jj * 4) = o4;
                }
            } else {
                u32x4 ob0, ob1, o8;
#pragma unroll
                for (int j = 0; j < 4; ++j) {
                    float v0 = Z[prow][pc0 + 2 * j];
                    float v1 = Z[prow][pc0 + 2 * j + 1];
                    float v2 = Z[prow][pc0 + 8 + 2 * j];
                    float v3 = Z[prow][pc0 + 8 + 2 * j + 1];
                    ob0[j] = (unsigned)f2bf(v0) | ((unsigned)f2bf(v1) << 16);
                    ob1[j] = (unsigned)f2bf(v2) | ((unsigned)f2bf(v3) << 16);
                    float w0 = Z[prow][pc0 + 4 * j], w1 = Z[prow][pc0 + 4 * j + 1];
                    float w2 = Z[prow][pc0 + 4 * j + 2], w3 = Z[prow][pc0 + 4 * j + 3];
                    o8[j] = (unsigned)f2fp8(w0) | ((unsigned)f2fp8(w1) << 8)
                          | ((unsigned)f2fp8(w2) << 16) | ((unsigned)f2fp8(w3) << 24);
                }
                *(u32x4*)(hout + ((size_t)grow << 7) + pc0)     = ob0;
                *(u32x4*)(hout + ((size_t)grow << 7) + pc0 + 8) = ob1;
                *(u32x4*)(h8out + ((size_t)grow << 7) + pc0)    = o8;
            }
        }
    }
}

// ---------------- launch ----------------

extern "C" void kernel_launch(void* const* d_in, const int* in_sizes, int n_in,
                              void* d_out, int out_size, void* d_ws, size_t ws_size,
                              hipStream_t stream) {
    const float* x    = (const float*)d_in[0];
    const int*   ei   = (const int*)d_in[1];
    const float* in_w = (const float*)d_in[2];
    const float* in_b = (const float*)d_in[3];
    const float* w1   = (const float*)d_in[4];
    const float* b1   = (const float*)d_in[5];
    const float* w2   = (const float*)d_in[6];
    const float* b2   = (const float*)d_in[7];
    const float* ln_g = (const float*)d_in[8];
    const float* ln_b = (const float*)d_in[9];

    const int N = in_sizes[0] / DIM;               // 50000
    const int E = in_sizes[1] / 2;                 // 640000
    const int LAYERS = in_sizes[4] / (DIM * DIM);  // 3

    const int* e_src = ei;
    const int* e_dst = ei + E;

    // workspace layout
    char* ws = (char*)d_ws;
    unsigned short* hb0    = (unsigned short*)ws;  ws += (size_t)N * DIM * 2;
    unsigned short* hb1    = (unsigned short*)ws;  ws += (size_t)N * DIM * 2;
    unsigned char*  h8a    = (unsigned char*)ws;   ws += (size_t)N * DIM;
    unsigned char*  h8b    = (unsigned char*)ws;   ws += (size_t)N * DIM;
    int*            counts = (int*)ws;             ws += (size_t)N * 4;
    int*            rowptr = (int*)ws;             ws += (size_t)(N + 1) * 4;
    int*            cursor = (int*)ws;             ws += (size_t)N * 4;
    float*          dinv   = (float*)ws;           ws += (size_t)N * 4;
    unsigned short* srcidx = (unsigned short*)ws;  ws += (size_t)E * 2;
    unsigned short* wt     = (unsigned short*)ws;  ws += (size_t)(2 * LAYERS + 1) * DIM * DIM * 2;
    unsigned short* mbuf   = (unsigned short*)ws;  ws += (size_t)N * DIM * 2;

    const int nScanBlocks = (N + 1023) / 1024;
    const int nMat = 2 * LAYERS + 1;
    const int nWblk = nMat * 8;

    // --- CSR build + weight cvt + input projection ---
    (void)hipMemsetAsync(counts, 0, (size_t)N * 4, stream);
    prep<<<nWblk + (E + 1023) / 1024, 256, 0, stream>>>(in_w, w1, w2, wt, LAYERS,
                                                        e_dst, E, counts, nWblk);
    scan_all<<<nScanBlocks, 256, 0, stream>>>(counts, N, rowptr, cursor, dinv, E);
    gemm_bias32<<<(N + 31) / 32, 256, 0, stream>>>(x, wt, in_b, hb0, h8a, N);
    fill_csr<<<(E + 1023) / 1024, 256, 0, stream>>>(e_src, e_dst, E, cursor, srcidx);

    const unsigned short* w1t = wt + (size_t)DIM * DIM;
    const unsigned short* w2t = wt + (size_t)(1 + LAYERS) * DIM * DIM;

    // --- layers (ping-pong; gather reads pre-update fp8 table) ---
    int tile_grid = (N + 31) / 32;
    unsigned short* hin  = hb0;  unsigned char* h8in  = h8a;
    unsigned short* hout = hb1;  unsigned char* h8out = h8b;
    for (int i = 0; i < LAYERS; ++i) {
        float* out = (i == LAYERS - 1) ? (float*)d_out : nullptr;
        aggregate<<<tile_grid, 256, 0, stream>>>(h8in, rowptr, srcidx, dinv, mbuf, N);
        mlp_ln<<<tile_grid, 256, 0, stream>>>(hin, mbuf,
                                              w1t + (size_t)i * DIM * DIM, b1 + (size_t)i * DIM,
                                              w2t + (size_t)i * DIM * DIM, b2 + (size_t)i * DIM,
                                              ln_g + (size_t)i * DIM, ln_b + (size_t)i * DIM,
                                              hout, h8out, out, N);
        unsigned short* t = hin; hin = hout; hout = t;
        unsigned char* t8 = h8in; h8in = h8out; h8out = t8;
    }
}